// Round 4
// baseline (1421.506 us; speedup 1.0000x reference)
//
#include <hip/hip_runtime.h>
#include <math.h>

#define B_   32
#define K_   2048
#define C_   256
#define P_   256
#define S_   16
#define OUTC 119

// output offsets (floats)
#define OFF0 0        // obj        (B,P,2)
#define OFF1 16384    // center     (B,P,3)
#define OFF2 40960    // size_scores(B,P,18)
#define OFF3 188416   // size_res   (B,P,18,3)
#define OFF4 630784   // pred_size  (B,P,3)
#define OFF5 655360   // sem        (B,P,18)
#define OFF6 802816   // corners    (B,P,8,3)
#define OFF7 999424   // sem_logits (B,P,19)
#define OFF8 1155072  // obj_prob   (B,P)
#define OFF9 1163264  // sem_prob   (B,P,18)

// transposed-weight workspace offsets (floats)
#define WT1_OFF 0         // 264 x 256 (rows 259..263 zero)
#define WT2_OFF 67584     // 256 x 256
#define WT3_OFF 133120    // 256 x 256

// X layout swizzle: logical float4-block j (samples 4j..4j+3) of row c stored
// at physical block ((j + (c>>2)) & 7). Reads stay wave-uniform broadcasts;
// epilogue b128 stores spread across all 32 banks (8-cycle optimal).
#define XIDX4(c, j)  ((c) * 32 + 4 * ((((j) + ((c) >> 2))) & 7))
// phead variant: 16 props per row, padded stride 20, 4 blocks
#define YIDX4(c, j)  ((c) * 20 + 4 * ((((j) + ((c) >> 2))) & 3))

__device__ __forceinline__ float sqdist_rn(float ax, float ay, float az,
                                           float bx, float by, float bz) {
  // numpy order: ((dx*dx + dy*dy) + dz*dz), no FMA contraction
  float dx = __fsub_rn(ax, bx), dy = __fsub_rn(ay, by), dz = __fsub_rn(az, bz);
  return __fadd_rn(__fadd_rn(__fmul_rn(dx, dx), __fmul_rn(dy, dy)),
                   __fmul_rn(dz, dz));
}

// --------------------------------------------------- weight transpose ------
// sa: wt[c][o] (264/256/256 rows); phead: pt1/pt2 [c][256], pt3 [c][120]
__global__ __launch_bounds__(256) void wtrans_kernel(
    const float* __restrict__ w1, const float* __restrict__ w2,
    const float* __restrict__ w3, const float* __restrict__ pw1,
    const float* __restrict__ pw2, const float* __restrict__ pw3,
    float* __restrict__ wt, float* __restrict__ pt1, float* __restrict__ pt2,
    float* __restrict__ pt3) {
  const int r = blockIdx.x, t = threadIdx.x;
  if (r < 264) {
    wt[WT1_OFF + r * 256 + t] = (r < 259) ? w1[t * 259 + r] : 0.f;
  } else if (r < 520) {
    const int c = r - 264;
    wt[WT2_OFF + c * 256 + t] = w2[t * 256 + c];
  } else if (r < 776) {
    const int c = r - 520;
    wt[WT3_OFF + c * 256 + t] = w3[t * 256 + c];
  } else if (r < 1032) {
    const int c = r - 776;
    pt1[c * 256 + t] = pw1[t * 256 + c];
  } else if (r < 1288) {
    const int c = r - 1032;
    pt2[c * 256 + t] = pw2[t * 256 + c];
  } else {
    const int c = r - 1288;
    if (t < 120) pt3[c * 120 + t] = (t < 119) ? pw3[t * 256 + c] : 0.f;
  }
}

// ---------------------------------------------------------------- FPS ------
__global__ __launch_bounds__(256) void fps_kernel(const float* __restrict__ xyz,
                                                  float* __restrict__ new_xyz) {
  const int b = blockIdx.x, t = threadIdx.x;
  const float* xb = xyz + b * K_ * 3;
  __shared__ __align__(16) float pts[K_ * 4];
  float px[8], py[8], pz[8], dist[8];
#pragma unroll
  for (int j = 0; j < 8; j++) {
    int k = t + 256 * j;
    px[j] = xb[3 * k + 0];
    py[j] = xb[3 * k + 1];
    pz[j] = xb[3 * k + 2];
    dist[j] = 1e10f;
    pts[4 * k + 0] = px[j];
    pts[4 * k + 1] = py[j];
    pts[4 * k + 2] = pz[j];
    pts[4 * k + 3] = 0.f;
  }
  __shared__ float s_val[4];
  __shared__ int s_idx[4];
  __shared__ int s_far;
  int far = 0;
  __syncthreads();
  for (int i = 0; i < P_; i++) {
    const float cx = pts[4 * far + 0];
    const float cy = pts[4 * far + 1];
    const float cz = pts[4 * far + 2];
    if (t == 0) {
      float* nx = new_xyz + (b * P_ + i) * 3;
      nx[0] = cx; nx[1] = cy; nx[2] = cz;
    }
    float bv = -1.0f;
    int bk = 0x7fffffff;
#pragma unroll
    for (int j = 0; j < 8; j++) {
      float d = sqdist_rn(px[j], py[j], pz[j], cx, cy, cz);
      dist[j] = fminf(dist[j], d);
      int k = t + 256 * j;
      if (dist[j] > bv || (dist[j] == bv && k < bk)) { bv = dist[j]; bk = k; }
    }
#pragma unroll
    for (int off = 32; off >= 1; off >>= 1) {
      float ov = __shfl_down(bv, off);
      int ok = __shfl_down(bk, off);
      if (ov > bv || (ov == bv && ok < bk)) { bv = ov; bk = ok; }
    }
    if ((t & 63) == 0) { s_val[t >> 6] = bv; s_idx[t >> 6] = bk; }
    __syncthreads();
    if (t == 0) {
      for (int w = 1; w < 4; w++) {
        float ov = s_val[w]; int ok = s_idx[w];
        if (ov > bv || (ov == bv && ok < bk)) { bv = ov; bk = ok; }
      }
      s_far = bk;
    }
    __syncthreads();
    far = s_far;
  }
}

// ---------------------------------------------------------- ball query -----
__global__ __launch_bounds__(256) void ballq_kernel(const float* __restrict__ xyz,
                                                    const float* __restrict__ new_xyz,
                                                    int* __restrict__ idxw) {
  const int b = blockIdx.x, t = threadIdx.x;
  __shared__ __align__(16) float pts[K_ * 4];
  const float* xb = xyz + b * K_ * 3;
#pragma unroll
  for (int j = 0; j < 8; j++) {
    int k = t + 256 * j;
    pts[4 * k + 0] = xb[3 * k + 0];
    pts[4 * k + 1] = xb[3 * k + 1];
    pts[4 * k + 2] = xb[3 * k + 2];
    pts[4 * k + 3] = 0.f;
  }
  __syncthreads();
  const float r2 = (float)(0.3 * 0.3);
  const int p = t;
  const float nx = new_xyz[(b * P_ + p) * 3 + 0];
  const float ny = new_xyz[(b * P_ + p) * 3 + 1];
  const float nz = new_xyz[(b * P_ + p) * 3 + 2];
  int* ob = idxw + (b * P_ + p) * S_;
  int cnt = 0, first = 0;
  for (int k = 0; k < K_; k++) {
    if (cnt >= S_) break;
    const float4 q = *(const float4*)&pts[4 * k];
    float d2 = sqdist_rn(q.x, q.y, q.z, nx, ny, nz);
    if (d2 < r2) {
      if (cnt == 0) first = k;
      ob[cnt] = k;
      cnt++;
    }
  }
  for (int s = cnt; s < S_; s++) ob[s] = first;
}

// ------------------------------------------------------------- SA MLP ------
// 2 proposals (32 samples)/block. X c-major swizzled in LDS (broadcast reads,
// conflict-free epilogue writes). W streamed straight from pre-transposed
// global (coalesced dwordx4, L2-hot), register-prefetched one chunk ahead —
// no W LDS round-trip, no per-chunk barriers (4 barriers total).
__global__ __launch_bounds__(256, 2) void sa_kernel(
    const float* __restrict__ xyz, const float* __restrict__ features,
    const float* __restrict__ wt, const float* __restrict__ gma,
    const float* __restrict__ bta, const float* __restrict__ mu,
    const float* __restrict__ var, const float* __restrict__ new_xyz,
    const int* __restrict__ idxw, float* __restrict__ y) {
  const int blk = blockIdx.x;                 // 4096 blocks
  const int b = blk >> 7, p0 = (blk & 127) * 2, t = threadIdx.x;
  __shared__ __align__(16) float XA[264 * 32];  // 33792 B
  __shared__ __align__(16) float XB[256 * 32];  // 32768 B
  __shared__ __align__(16) float red[4 * 256];  // 4096 B
  __shared__ int k_sh[32];

  // ---- gather ----
  if (t < 32) k_sh[t] = idxw[(b * P_ + p0) * S_ + t];
  if (t < 160) XA[259 * 32 + t] = 0.f;  // rows 259..263 zero (any swizzle)
  __syncthreads();
  if (t < 32) {
    const int pl = t >> 4;
    const int k = k_sh[t];
    const float* xb = xyz + b * K_ * 3;
    const float* nx = new_xyz + (b * P_ + p0 + pl) * 3;
    // rows 0..2 have rotation 0 -> plain layout
    XA[0 * 32 + t] = (xb[3 * k + 0] - nx[0]) / 0.3f;
    XA[1 * 32 + t] = (xb[3 * k + 1] - nx[1]) / 0.3f;
    XA[2 * 32 + t] = (xb[3 * k + 2] - nx[2]) / 0.3f;
  }
  {
    const float* fb = features + (size_t)b * C_ * K_ + (size_t)t * K_;
    const int c = 3 + t;
#pragma unroll 8
    for (int s = 0; s < 32; s++) {
      XA[XIDX4(c, (s >> 2)) + (s & 3)] = fb[k_sh[s]];
    }
  }
  __syncthreads();

  const int og = t & 63;   // outputs 4*og .. 4*og+3
  const int sg = t >> 6;   // samples 8*sg .. 8*sg+7 (wave-uniform)
  const int o4 = og * 4;
  const int j0 = sg * 2;   // logical float4 s-blocks j0, j0+1

  float acc[4][8];
  float4 wreg[8];
#pragma unroll
  for (int j = 0; j < 8; j++)
    wreg[j] = *(const float4*)&wt[WT1_OFF + j * 256 + o4];

  for (int l = 0; l < 3; l++) {
    const float* wtl = wt + ((l == 0) ? WT1_OFF : (l == 1) ? WT2_OFF : WT3_OFF);
    const float* wtnext = (l == 0) ? (wt + WT2_OFF) : (wt + WT3_OFF);
    const float* Xin = (l == 1) ? XB : XA;
    float* Xout = (l == 0) ? XB : XA;
    const int nch = (l == 0) ? 33 : 32;
#pragma unroll
    for (int i = 0; i < 4; i++)
#pragma unroll
      for (int j = 0; j < 8; j++) acc[i][j] = 0.f;

    for (int ch = 0; ch < nch; ch++) {
      float4 wv[8];
#pragma unroll
      for (int j = 0; j < 8; j++) wv[j] = wreg[j];
      {
        const float* pn = (ch + 1 < nch) ? (wtl + (ch + 1) * 2048)
                                         : ((l < 2) ? wtnext : nullptr);
        if (pn) {
#pragma unroll
          for (int j = 0; j < 8; j++)
            wreg[j] = *(const float4*)&pn[j * 256 + o4];
        }
      }
#pragma unroll
      for (int j = 0; j < 8; j++) {
        const int c = ch * 8 + j;
        const float4 x0 = *(const float4*)&Xin[XIDX4(c, j0)];
        const float4 x1 = *(const float4*)&Xin[XIDX4(c, j0 + 1)];
        const float wvv[4] = {wv[j].x, wv[j].y, wv[j].z, wv[j].w};
        const float xs[8] = {x0.x, x0.y, x0.z, x0.w, x1.x, x1.y, x1.z, x1.w};
#pragma unroll
        for (int i = 0; i < 4; i++)
#pragma unroll
          for (int jj = 0; jj < 8; jj++)
            acc[i][jj] = fmaf(wvv[i], xs[jj], acc[i][jj]);
      }
    }

    if (l < 2) {
      const float4 g4 = *(const float4*)&gma[l * 256 + o4];
      const float4 v4 = *(const float4*)&var[l * 256 + o4];
      const float4 m4 = *(const float4*)&mu[l * 256 + o4];
      const float4 b4 = *(const float4*)&bta[l * 256 + o4];
      const float sc[4] = {g4.x / sqrtf(v4.x + 1e-5f), g4.y / sqrtf(v4.y + 1e-5f),
                           g4.z / sqrtf(v4.z + 1e-5f), g4.w / sqrtf(v4.w + 1e-5f)};
      const float mm[4] = {m4.x, m4.y, m4.z, m4.w};
      const float bb[4] = {b4.x, b4.y, b4.z, b4.w};
#pragma unroll
      for (int i = 0; i < 4; i++) {
        float4 r0, r1;
        r0.x = fmaxf((acc[i][0] - mm[i]) * sc[i] + bb[i], 0.f);
        r0.y = fmaxf((acc[i][1] - mm[i]) * sc[i] + bb[i], 0.f);
        r0.z = fmaxf((acc[i][2] - mm[i]) * sc[i] + bb[i], 0.f);
        r0.w = fmaxf((acc[i][3] - mm[i]) * sc[i] + bb[i], 0.f);
        r1.x = fmaxf((acc[i][4] - mm[i]) * sc[i] + bb[i], 0.f);
        r1.y = fmaxf((acc[i][5] - mm[i]) * sc[i] + bb[i], 0.f);
        r1.z = fmaxf((acc[i][6] - mm[i]) * sc[i] + bb[i], 0.f);
        r1.w = fmaxf((acc[i][7] - mm[i]) * sc[i] + bb[i], 0.f);
        *(float4*)&Xout[XIDX4(o4 + i, j0)] = r0;
        *(float4*)&Xout[XIDX4(o4 + i, j0 + 1)] = r1;
      }
      __syncthreads();  // Xout visible before next layer's K-loop
    } else {
      float rr[4];
#pragma unroll
      for (int i = 0; i < 4; i++) {
        float m = acc[i][0];
#pragma unroll
        for (int j = 1; j < 8; j++) m = fmaxf(m, acc[i][j]);
        rr[i] = m;
      }
      float4 r;
      r.x = rr[0]; r.y = rr[1]; r.z = rr[2]; r.w = rr[3];
      *(float4*)&red[sg * 256 + o4] = r;
      __syncthreads();
      const float sc2 = gma[512 + t] / sqrtf(var[512 + t] + 1e-5f);
      const float mu2 = mu[512 + t], bt2 = bta[512 + t];
#pragma unroll
      for (int pl = 0; pl < 2; pl++) {
        const float raw = fmaxf(red[(2 * pl) * 256 + t], red[(2 * pl + 1) * 256 + t]);
        y[(b * P_ + p0 + pl) * 256 + t] = fmaxf((raw - mu2) * sc2 + bt2, 0.f);
      }
    }
  }
}

// ------------------------------------------------- P-layers + all heads ----
// Same structure as sa: X (16 props) c-major swizzled in LDS, W streamed from
// pre-transposed global with register prefetch, barriers only between layers.
__global__ __launch_bounds__(256, 2) void phead_kernel(
    const float* __restrict__ y, const float* __restrict__ pt1,
    const float* __restrict__ pt2, const float* __restrict__ pt3,
    const float* __restrict__ pb3, const float* __restrict__ pg,
    const float* __restrict__ pb, const float* __restrict__ pm,
    const float* __restrict__ pv, const float* __restrict__ new_xyz,
    const float* __restrict__ msa, float* __restrict__ out) {
  const int blk = blockIdx.x;
  const int b = blk >> 4, p0 = (blk & 15) * 16, t = threadIdx.x;
  __shared__ __align__(16) float Yt[256 * 20];   // 20480 B
  __shared__ __align__(16) float Ht[256 * 20];   // 20480 B
  __shared__ float net_s[16 * 120];

  for (int u = t; u < 16 * 256; u += 256) {
    const int pl = u >> 8, c = u & 255;
    Yt[YIDX4(c, (pl >> 2)) + (pl & 3)] = y[(b * P_ + p0 + pl) * C_ + c];
  }
  __syncthreads();

  const int og = t & 63, pgp = t >> 6;
  const int o4 = og * 4;
  float acc[4][4];
  float4 wreg[8];
#pragma unroll
  for (int j = 0; j < 8; j++) wreg[j] = *(const float4*)&pt1[j * 256 + o4];

  for (int l = 0; l < 2; l++) {
    const float* wtl = l ? pt2 : pt1;
    const float* Xin = l ? Ht : Yt;
    float* Xout = l ? Yt : Ht;
#pragma unroll
    for (int i = 0; i < 4; i++)
#pragma unroll
      for (int k = 0; k < 4; k++) acc[i][k] = 0.f;

    for (int ch = 0; ch < 32; ch++) {
      float4 wv[8];
#pragma unroll
      for (int j = 0; j < 8; j++) wv[j] = wreg[j];
      if (ch + 1 < 32) {
        const float* pn = wtl + (ch + 1) * 2048;
#pragma unroll
        for (int j = 0; j < 8; j++) wreg[j] = *(const float4*)&pn[j * 256 + o4];
      } else if (l == 0) {
#pragma unroll
        for (int j = 0; j < 8; j++) wreg[j] = *(const float4*)&pt2[j * 256 + o4];
      } else {
#pragma unroll
        for (int j = 0; j < 8; j++) wreg[j] = *(const float4*)&pt3[j * 120 + o4];
      }
#pragma unroll
      for (int j = 0; j < 8; j++) {
        const int c = ch * 8 + j;
        const float4 xv = *(const float4*)&Xin[YIDX4(c, pgp)];
        const float wvv[4] = {wv[j].x, wv[j].y, wv[j].z, wv[j].w};
        const float xs[4] = {xv.x, xv.y, xv.z, xv.w};
#pragma unroll
        for (int i = 0; i < 4; i++)
#pragma unroll
          for (int k = 0; k < 4; k++)
            acc[i][k] = fmaf(wvv[i], xs[k], acc[i][k]);
      }
    }
    {
      const float4 g4 = *(const float4*)&pg[l * 256 + o4];
      const float4 v4 = *(const float4*)&pv[l * 256 + o4];
      const float4 m4 = *(const float4*)&pm[l * 256 + o4];
      const float4 b4 = *(const float4*)&pb[l * 256 + o4];
      const float sc[4] = {g4.x / sqrtf(v4.x + 1e-5f), g4.y / sqrtf(v4.y + 1e-5f),
                           g4.z / sqrtf(v4.z + 1e-5f), g4.w / sqrtf(v4.w + 1e-5f)};
      const float mm[4] = {m4.x, m4.y, m4.z, m4.w};
      const float bb[4] = {b4.x, b4.y, b4.z, b4.w};
#pragma unroll
      for (int i = 0; i < 4; i++) {
        float4 r;
        r.x = fmaxf((acc[i][0] - mm[i]) * sc[i] + bb[i], 0.f);
        r.y = fmaxf((acc[i][1] - mm[i]) * sc[i] + bb[i], 0.f);
        r.z = fmaxf((acc[i][2] - mm[i]) * sc[i] + bb[i], 0.f);
        r.w = fmaxf((acc[i][3] - mm[i]) * sc[i] + bb[i], 0.f);
        *(float4*)&Xout[YIDX4(o4 + i, pgp)] = r;
      }
    }
    __syncthreads();
  }

  // final layer: 120 padded outputs (col 119 zero weights), reads Yt
  {
#pragma unroll
    for (int i = 0; i < 4; i++)
#pragma unroll
      for (int k = 0; k < 4; k++) acc[i][k] = 0.f;
    for (int ch = 0; ch < 32; ch++) {
      float4 wv[8];
#pragma unroll
      for (int j = 0; j < 8; j++) wv[j] = wreg[j];
      if (ch + 1 < 32) {
        const float* pn = pt3 + (ch + 1) * 8 * 120;
#pragma unroll
        for (int j = 0; j < 8; j++) wreg[j] = *(const float4*)&pn[j * 120 + o4];
      }
#pragma unroll
      for (int j = 0; j < 8; j++) {
        const int c = ch * 8 + j;
        const float4 xv = *(const float4*)&Yt[YIDX4(c, pgp)];
        const float wvv[4] = {wv[j].x, wv[j].y, wv[j].z, wv[j].w};
        const float xs[4] = {xv.x, xv.y, xv.z, xv.w};
#pragma unroll
        for (int i = 0; i < 4; i++)
#pragma unroll
          for (int k = 0; k < 4; k++)
            acc[i][k] = fmaf(wvv[i], xs[k], acc[i][k]);
      }
    }
    if (og < 30) {
#pragma unroll
      for (int i = 0; i < 4; i++) {
        const int o = o4 + i;
        const float bb = (o < 119) ? pb3[o] : 0.f;
#pragma unroll
        for (int k = 0; k < 4; k++)
          net_s[(pgp * 4 + k) * 120 + o] = acc[i][k] + bb;
      }
    }
  }
  __syncthreads();

  // heads: one thread per proposal
  if (t < 16) {
    const int pg_i = p0 + t;
    const int gi = b * P_ + pg_i;
    const float* nr = &net_s[t * 120];
    const float nx = new_xyz[gi * 3 + 0];
    const float ny = new_xyz[gi * 3 + 1];
    const float nz = new_xyz[gi * 3 + 2];
    const float obj0 = nr[0], obj1 = nr[1];
    out[OFF0 + gi * 2 + 0] = obj0;
    out[OFF0 + gi * 2 + 1] = obj1;
    const float cx = nx + nr[2], cy = ny + nr[3], cz = nz + nr[4];
    out[OFF1 + gi * 3 + 0] = cx;
    out[OFF1 + gi * 3 + 1] = cy;
    out[OFF1 + gi * 3 + 2] = cz;
    float bv = -1e30f;
    int bi = 0;
#pragma unroll
    for (int i = 0; i < 18; i++) {
      float v = nr[29 + i];
      out[OFF2 + gi * 18 + i] = v;
      if (v > bv) { bv = v; bi = i; }
    }
#pragma unroll
    for (int i = 0; i < 18; i++)
#pragma unroll
      for (int j = 0; j < 3; j++)
        out[OFF3 + gi * 54 + i * 3 + j] =
            __fmul_rn(nr[47 + i * 3 + j], msa[i * 3 + j]);
    float ps[3];
#pragma unroll
    for (int j = 0; j < 3; j++) {
      ps[j] = __fadd_rn(__fmul_rn(nr[47 + bi * 3 + j], msa[bi * 3 + j]),
                        msa[bi * 3 + j]);
      out[OFF4 + gi * 3 + j] = ps[j];
    }
    float sm = -1e30f;
#pragma unroll
    for (int i = 0; i < 18; i++) {
      float v = nr[101 + i];
      out[OFF5 + gi * 18 + i] = v;
      out[OFF7 + gi * 19 + i] = v;
      sm = fmaxf(sm, v);
    }
    out[OFF7 + gi * 19 + 18] = (obj0 <= obj1) ? 0.f : 1e10f;
    const float cc0 = cx, cc1 = cz, cc2 = -cy;
    const float sxk[8] = {1, 1, -1, -1, 1, 1, -1, -1};
    const float syk[8] = {1, 1, 1, 1, -1, -1, -1, -1};
    const float szk[8] = {1, -1, -1, 1, 1, -1, -1, 1};
#pragma unroll
    for (int k = 0; k < 8; k++) {
      out[OFF6 + gi * 24 + 3 * k + 0] = cc0 + ps[0] * sxk[k] * 0.5f;
      out[OFF6 + gi * 24 + 3 * k + 1] = cc1 + ps[2] * syk[k] * 0.5f;
      out[OFF6 + gi * 24 + 3 * k + 2] = cc2 + ps[1] * szk[k] * 0.5f;
    }
    {
      const float m2 = fmaxf(obj0, obj1);
      const float e0 = expf(obj0 - m2), e1 = expf(obj1 - m2);
      out[OFF8 + gi] = e1 / (e0 + e1);
    }
    {
      float ev[18], es = 0.f;
#pragma unroll
      for (int i = 0; i < 18; i++) {
        ev[i] = expf(nr[101 + i] - sm);
        es += ev[i];
      }
#pragma unroll
      for (int i = 0; i < 18; i++) out[OFF9 + gi * 18 + i] = ev[i] / es;
    }
  }
}

// ---------------------------------------------------------------------------
extern "C" void kernel_launch(void* const* d_in, const int* in_sizes, int n_in,
                              void* d_out, int out_size, void* d_ws,
                              size_t ws_size, hipStream_t stream) {
  (void)in_sizes; (void)n_in; (void)out_size; (void)ws_size;
  const float* xyz      = (const float*)d_in[0];
  const float* features = (const float*)d_in[1];
  const float* w1       = (const float*)d_in[2];
  const float* w2       = (const float*)d_in[3];
  const float* w3       = (const float*)d_in[4];
  const float* gma      = (const float*)d_in[5];
  const float* bta      = (const float*)d_in[6];
  const float* mu       = (const float*)d_in[7];
  const float* var      = (const float*)d_in[8];
  const float* pw1      = (const float*)d_in[9];
  const float* pw2      = (const float*)d_in[10];
  const float* pw3      = (const float*)d_in[11];
  const float* pb3      = (const float*)d_in[12];
  const float* pg       = (const float*)d_in[13];
  const float* pb       = (const float*)d_in[14];
  const float* pm       = (const float*)d_in[15];
  const float* pv       = (const float*)d_in[16];
  const float* msa      = (const float*)d_in[17];
  float* out = (float*)d_out;

  char* ws = (char*)d_ws;
  float* new_xyz = (float*)ws;                  // 98304 B
  int*   idxw    = (int*)(ws + 98304);          // 524288 B
  float* yb      = (float*)(ws + 622592);       // 8388608 B
  float* wt      = (float*)(ws + 9011200);      // 794624 B
  float* pt1     = (float*)(ws + 9805824);      // 262144 B
  float* pt2     = (float*)(ws + 10067968);     // 262144 B
  float* pt3     = (float*)(ws + 10330112);     // 126976 B (incl. pad)

  wtrans_kernel<<<1544, 256, 0, stream>>>(w1, w2, w3, pw1, pw2, pw3, wt, pt1,
                                          pt2, pt3);
  fps_kernel<<<B_, 256, 0, stream>>>(xyz, new_xyz);
  ballq_kernel<<<B_, 256, 0, stream>>>(xyz, new_xyz, idxw);
  sa_kernel<<<B_ * 128, 256, 0, stream>>>(xyz, features, wt, gma, bta, mu, var,
                                          new_xyz, idxw, yb);
  phead_kernel<<<B_ * 16, 256, 0, stream>>>(yb, pt1, pt2, pt3, pb3, pg, pb, pm,
                                            pv, new_xyz, msa, out);
}

// Round 5
// 904.106 us; speedup vs baseline: 1.5723x; 1.5723x over previous
//
#include <hip/hip_runtime.h>
#include <math.h>

#define B_   32
#define K_   2048
#define C_   256
#define P_   256
#define S_   16
#define OUTC 119

// output offsets (floats)
#define OFF0 0        // obj        (B,P,2)
#define OFF1 16384    // center     (B,P,3)
#define OFF2 40960    // size_scores(B,P,18)
#define OFF3 188416   // size_res   (B,P,18,3)
#define OFF4 630784   // pred_size  (B,P,3)
#define OFF5 655360   // sem        (B,P,18)
#define OFF6 802816   // corners    (B,P,8,3)
#define OFF7 999424   // sem_logits (B,P,19)
#define OFF8 1155072  // obj_prob   (B,P)
#define OFF9 1163264  // sem_prob   (B,P,18)

typedef _Float16 half8  __attribute__((ext_vector_type(8)));
typedef _Float16 half4h __attribute__((ext_vector_type(4)));
typedef float    f32x4  __attribute__((ext_vector_type(4)));
#define MFMA16 __builtin_amdgcn_mfma_f32_16x16x32_f16

__device__ __forceinline__ float sqdist_rn(float ax, float ay, float az,
                                           float bx, float by, float bz) {
  float dx = __fsub_rn(ax, bx), dy = __fsub_rn(ay, by), dz = __fsub_rn(az, bz);
  return __fadd_rn(__fadd_rn(__fmul_rn(dx, dx), __fmul_rn(dy, dy)),
                   __fmul_rn(dz, dz));
}

// ------------------------------------------- weight split to f16 hi/lo -----
// Fragment-order layout: Wf[tile = ot*nks + ks][lane][8], so an A-frag load
// is one coalesced 1KB wave read. l0 padded K 259->288 (9 k-steps).
__global__ __launch_bounds__(64) void wsplit_kernel(
    const float* __restrict__ w1, const float* __restrict__ w2,
    const float* __restrict__ w3, const float* __restrict__ gma,
    const float* __restrict__ var, _Float16* __restrict__ w1h,
    _Float16* __restrict__ w1l, _Float16* __restrict__ w2h,
    _Float16* __restrict__ w2l, _Float16* __restrict__ w3h,
    _Float16* __restrict__ w3l, float* __restrict__ bns) {
  const int r = blockIdx.x, t = threadIdx.x;
  if (r == 400) {
    for (int u = t; u < 768; u += 64) bns[u] = gma[u] / sqrtf(var[u] + 1e-5f);
    return;
  }
  const float* src;
  _Float16 *dh, *dl;
  int ot, ks, nks, K;
  if (r < 144) {
    src = w1; dh = w1h; dl = w1l; ot = r / 9; ks = r % 9; nks = 9; K = 259;
  } else if (r < 272) {
    const int rr = r - 144;
    src = w2; dh = w2h; dl = w2l; ot = rr >> 3; ks = rr & 7; nks = 8; K = 256;
  } else {
    const int rr = r - 272;
    src = w3; dh = w3h; dl = w3l; ot = rr >> 3; ks = rr & 7; nks = 8; K = 256;
  }
  const int m = t & 15, q = t >> 4;
  const float* row = src + (ot * 16 + m) * K;
  half8 vh, vl;
#pragma unroll
  for (int j = 0; j < 8; j++) {
    const int c = ks * 32 + q * 8 + j;
    const float v = (c < K) ? row[c] : 0.f;
    const _Float16 hi = (_Float16)v;
    vh[j] = hi;
    vl[j] = (_Float16)(v - (float)hi);
  }
  const int base = ((ot * nks + ks) * 64 + t) * 8;
  *(half8*)&dh[base] = vh;
  *(half8*)&dl[base] = vl;
}

// ---------------------------------------------------------------- FPS ------
__global__ __launch_bounds__(256) void fps_kernel(const float* __restrict__ xyz,
                                                  float* __restrict__ new_xyz) {
  const int b = blockIdx.x, t = threadIdx.x;
  const float* xb = xyz + b * K_ * 3;
  __shared__ __align__(16) float pts[K_ * 4];
  float px[8], py[8], pz[8], dist[8];
#pragma unroll
  for (int j = 0; j < 8; j++) {
    int k = t + 256 * j;
    px[j] = xb[3 * k + 0];
    py[j] = xb[3 * k + 1];
    pz[j] = xb[3 * k + 2];
    dist[j] = 1e10f;
    pts[4 * k + 0] = px[j];
    pts[4 * k + 1] = py[j];
    pts[4 * k + 2] = pz[j];
    pts[4 * k + 3] = 0.f;
  }
  __shared__ float s_val[4];
  __shared__ int s_idx[4];
  __shared__ int s_far;
  int far = 0;
  __syncthreads();
  for (int i = 0; i < P_; i++) {
    const float cx = pts[4 * far + 0];
    const float cy = pts[4 * far + 1];
    const float cz = pts[4 * far + 2];
    if (t == 0) {
      float* nx = new_xyz + (b * P_ + i) * 3;
      nx[0] = cx; nx[1] = cy; nx[2] = cz;
    }
    float bv = -1.0f;
    int bk = 0x7fffffff;
#pragma unroll
    for (int j = 0; j < 8; j++) {
      float d = sqdist_rn(px[j], py[j], pz[j], cx, cy, cz);
      dist[j] = fminf(dist[j], d);
      int k = t + 256 * j;
      if (dist[j] > bv || (dist[j] == bv && k < bk)) { bv = dist[j]; bk = k; }
    }
#pragma unroll
    for (int off = 32; off >= 1; off >>= 1) {
      float ov = __shfl_down(bv, off);
      int ok = __shfl_down(bk, off);
      if (ov > bv || (ov == bv && ok < bk)) { bv = ov; bk = ok; }
    }
    if ((t & 63) == 0) { s_val[t >> 6] = bv; s_idx[t >> 6] = bk; }
    __syncthreads();
    if (t == 0) {
      for (int w = 1; w < 4; w++) {
        float ov = s_val[w]; int ok = s_idx[w];
        if (ov > bv || (ov == bv && ok < bk)) { bv = ov; bk = ok; }
      }
      s_far = bk;
    }
    __syncthreads();
    far = s_far;
  }
}

// ---------------------------------------------------------- ball query -----
__global__ __launch_bounds__(256) void ballq_kernel(const float* __restrict__ xyz,
                                                    const float* __restrict__ new_xyz,
                                                    int* __restrict__ idxw) {
  const int b = blockIdx.x, t = threadIdx.x;
  __shared__ __align__(16) float pts[K_ * 4];
  const float* xb = xyz + b * K_ * 3;
#pragma unroll
  for (int j = 0; j < 8; j++) {
    int k = t + 256 * j;
    pts[4 * k + 0] = xb[3 * k + 0];
    pts[4 * k + 1] = xb[3 * k + 1];
    pts[4 * k + 2] = xb[3 * k + 2];
    pts[4 * k + 3] = 0.f;
  }
  __syncthreads();
  const float r2 = (float)(0.3 * 0.3);
  const int p = t;
  const float nx = new_xyz[(b * P_ + p) * 3 + 0];
  const float ny = new_xyz[(b * P_ + p) * 3 + 1];
  const float nz = new_xyz[(b * P_ + p) * 3 + 2];
  int* ob = idxw + (b * P_ + p) * S_;
  int cnt = 0, first = 0;
  for (int k = 0; k < K_; k++) {
    if (cnt >= S_) break;
    const float4 q = *(const float4*)&pts[4 * k];
    float d2 = sqdist_rn(q.x, q.y, q.z, nx, ny, nz);
    if (d2 < r2) {
      if (cnt == 0) first = k;
      ob[cnt] = k;
      cnt++;
    }
  }
  for (int s = cnt; s < S_; s++) ob[s] = first;
}

// ------------------------------------------------------------- SA MLP ------
// Split-f16 MFMA: D = Wh*Xh + Wh*Xl + Wl*Xh (error ~2^-22, below f32-reorder
// noise). 2 proposals (32 samples)/block, 4 waves; wave w: o-tiles 4w..4w+3,
// both s-tiles. A-frags streamed from fragment-order global W (coalesced,
// prefetched one k-step ahead); B-frags from LDS X [s][c] f16 hi/lo.
// Layouts (HW-verified): A[m=lane&15][k=q*8+j], B[n=lane&15][k=q*8+j],
// C/D col=lane&15 (sample), row=q*4+reg (output).
__global__ __launch_bounds__(256, 2) void sa_kernel(
    const float* __restrict__ xyz, const float* __restrict__ features,
    const _Float16* __restrict__ w1h, const _Float16* __restrict__ w1l,
    const _Float16* __restrict__ w2h, const _Float16* __restrict__ w2l,
    const _Float16* __restrict__ w3h, const _Float16* __restrict__ w3l,
    const float* __restrict__ bns, const float* __restrict__ mu,
    const float* __restrict__ bta, const float* __restrict__ new_xyz,
    const int* __restrict__ idxw, float* __restrict__ y) {
  const int blk = blockIdx.x;  // 4096
  const int b = blk >> 7, p0 = (blk & 127) * 2, t = threadIdx.x;
  __shared__ __align__(16) _Float16 X1h[32 * 296];  // 18944 B
  __shared__ __align__(16) _Float16 X1l[32 * 296];
  __shared__ __align__(16) _Float16 X2h[32 * 264];  // 16896 B
  __shared__ __align__(16) _Float16 X2l[32 * 264];
  __shared__ __align__(16) float red[2 * 256];
  __shared__ int k_sh[32];

  if (t < 32) k_sh[t] = idxw[(b * P_ + p0) * S_ + t];
  // zero pad c in [259,288) (read by k-step 8 of layer 0)
  for (int u = t; u < 32 * 32; u += 256) {
    const int s = u >> 5, cc = 256 + (u & 31);
    if (cc >= 259) {
      X1h[s * 296 + cc] = (_Float16)0.f;
      X1l[s * 296 + cc] = (_Float16)0.f;
    }
  }
  __syncthreads();
  if (t < 32) {
    const int pl = t >> 4, k = k_sh[t];
    const float* xb = xyz + b * K_ * 3;
    const float* nx = new_xyz + (b * P_ + p0 + pl) * 3;
#pragma unroll
    for (int c = 0; c < 3; c++) {
      const float v = (xb[3 * k + c] - nx[c]) / 0.3f;
      const _Float16 hi = (_Float16)v;
      X1h[t * 296 + c] = hi;
      X1l[t * 296 + c] = (_Float16)(v - (float)hi);
    }
  }
  {
    const float* fb = features + (size_t)b * C_ * K_ + (size_t)t * K_;
    const int c = 3 + t;
#pragma unroll 8
    for (int s = 0; s < 32; s++) {
      const float v = fb[k_sh[s]];
      const _Float16 hi = (_Float16)v;
      X1h[s * 296 + c] = hi;
      X1l[s * 296 + c] = (_Float16)(v - (float)hi);
    }
  }

  const int lane = t & 63, w = t >> 6;
  const int m = lane & 15, q = lane >> 4;

  f32x4 acc[4][2];
  half8 pAh[4], pAl[4];
#pragma unroll
  for (int i = 0; i < 4; i++) {  // prefetch layer0 ks=0
    const int off = (((4 * w + i) * 9) * 64 + lane) * 8;
    pAh[i] = *(const half8*)&w1h[off];
    pAl[i] = *(const half8*)&w1l[off];
  }
  __syncthreads();

#pragma unroll
  for (int l = 0; l < 3; l++) {
    const _Float16* Xih = (l == 1) ? X2h : X1h;
    const _Float16* Xil = (l == 1) ? X2l : X1l;
    const int XS = (l == 1) ? 264 : 296;
    const int nks = (l == 0) ? 9 : 8;
#pragma unroll
    for (int i = 0; i < 4; i++) {
      acc[i][0] = (f32x4){0.f, 0.f, 0.f, 0.f};
      acc[i][1] = (f32x4){0.f, 0.f, 0.f, 0.f};
    }
    for (int ks = 0; ks < nks; ks++) {
      half8 Ah[4], Al[4];
#pragma unroll
      for (int i = 0; i < 4; i++) { Ah[i] = pAh[i]; Al[i] = pAl[i]; }
      {  // prefetch next k-step (or next layer's ks=0)
        int ln = l, kn = ks + 1;
        if (kn == nks) { ln = l + 1; kn = 0; }
        if (ln < 3) {
          const _Float16* Ph = (ln == 0) ? w1h : (ln == 1) ? w2h : w3h;
          const _Float16* Pl = (ln == 0) ? w1l : (ln == 1) ? w2l : w3l;
          const int nk2 = (ln == 0) ? 9 : 8;
#pragma unroll
          for (int i = 0; i < 4; i++) {
            const int off = (((4 * w + i) * nk2 + kn) * 64 + lane) * 8;
            pAh[i] = *(const half8*)&Ph[off];
            pAl[i] = *(const half8*)&Pl[off];
          }
        }
      }
      const int xo = ks * 32 + q * 8;
      const half8 Bh0 = *(const half8*)&Xih[m * XS + xo];
      const half8 Bl0 = *(const half8*)&Xil[m * XS + xo];
      const half8 Bh1 = *(const half8*)&Xih[(16 + m) * XS + xo];
      const half8 Bl1 = *(const half8*)&Xil[(16 + m) * XS + xo];
#pragma unroll
      for (int i = 0; i < 4; i++) {
        acc[i][0] = MFMA16(Ah[i], Bh0, acc[i][0], 0, 0, 0);
        acc[i][0] = MFMA16(Ah[i], Bl0, acc[i][0], 0, 0, 0);
        acc[i][0] = MFMA16(Al[i], Bh0, acc[i][0], 0, 0, 0);
        acc[i][1] = MFMA16(Ah[i], Bh1, acc[i][1], 0, 0, 0);
        acc[i][1] = MFMA16(Ah[i], Bl1, acc[i][1], 0, 0, 0);
        acc[i][1] = MFMA16(Al[i], Bh1, acc[i][1], 0, 0, 0);
      }
    }

    if (l < 2) {
      _Float16* Xoh = (l == 0) ? X2h : X1h;
      _Float16* Xol = (l == 0) ? X2l : X1l;
      const int XSo = (l == 0) ? 264 : 296;
#pragma unroll
      for (int i = 0; i < 4; i++) {
        const int ob = (4 * w + i) * 16 + q * 4;
        const f32x4 sc4 = *(const f32x4*)&bns[l * 256 + ob];
        const f32x4 m4 = *(const f32x4*)&mu[l * 256 + ob];
        const f32x4 b4 = *(const f32x4*)&bta[l * 256 + ob];
#pragma unroll
        for (int s = 0; s < 2; s++) {
          half4h vh, vl;
#pragma unroll
          for (int r = 0; r < 4; r++) {
            const float v = fmaxf((acc[i][s][r] - m4[r]) * sc4[r] + b4[r], 0.f);
            const _Float16 hi = (_Float16)v;
            vh[r] = hi;
            vl[r] = (_Float16)(v - (float)hi);
          }
          const int scol = s * 16 + m;
          *(half4h*)&Xoh[scol * XSo + ob] = vh;
          *(half4h*)&Xol[scol * XSo + ob] = vl;
        }
      }
      __syncthreads();
    } else {
      // maxpool over 16 sample-cols (lanes n=0..15 within each q group)
#pragma unroll
      for (int i = 0; i < 4; i++)
#pragma unroll
        for (int s = 0; s < 2; s++)
#pragma unroll
          for (int r = 0; r < 4; r++) {
            float v = acc[i][s][r];
            v = fmaxf(v, __shfl_xor(v, 1));
            v = fmaxf(v, __shfl_xor(v, 2));
            v = fmaxf(v, __shfl_xor(v, 4));
            v = fmaxf(v, __shfl_xor(v, 8));
            acc[i][s][r] = v;
          }
      if (m == 0) {
#pragma unroll
        for (int i = 0; i < 4; i++) {
          const int ob = (4 * w + i) * 16 + q * 4;
          *(f32x4*)&red[ob] = acc[i][0];
          *(f32x4*)&red[256 + ob] = acc[i][1];
        }
      }
      __syncthreads();
      const float sc2 = bns[512 + t];
      const float mu2 = mu[512 + t], bt2 = bta[512 + t];
#pragma unroll
      for (int pl = 0; pl < 2; pl++) {
        const float raw = red[pl * 256 + t];
        y[(b * P_ + p0 + pl) * 256 + t] = fmaxf((raw - mu2) * sc2 + bt2, 0.f);
      }
    }
  }
}

// ------------------------------------------------- P-layers + all heads ----
#define PHST 260
__global__ __launch_bounds__(256, 2) void phead_kernel(
    const float* __restrict__ y, const float* __restrict__ pw1,
    const float* __restrict__ pw2, const float* __restrict__ pw3,
    const float* __restrict__ pb3, const float* __restrict__ pg,
    const float* __restrict__ pb, const float* __restrict__ pm,
    const float* __restrict__ pv, const float* __restrict__ new_xyz,
    const float* __restrict__ msa, float* __restrict__ out) {
  const int blk = blockIdx.x;
  const int b = blk >> 4, p0 = (blk & 15) * 16, t = threadIdx.x;
  __shared__ __align__(16) float Yt[16 * PHST];
  __shared__ __align__(16) float Ht[16 * PHST];
  __shared__ __align__(16) float Wt[256 * 20];
  __shared__ float net_s[16 * 120];

  for (int u = t; u < 16 * 256; u += 256) {
    int pl = u >> 8, c = u & 255;
    Yt[pl * PHST + c] = y[(b * P_ + p0 + pl) * C_ + c];
  }
  __syncthreads();

  const int oA = t & 127, oB = oA + 128, pB = (t >> 7) * 8;
  float accA[8], accB[8];
  for (int l = 0; l < 2; l++) {
    const float* w = l ? pw2 : pw1;
    const float* inb = l ? Ht : Yt;
    float* outb = l ? Yt : Ht;
#pragma unroll
    for (int pp = 0; pp < 8; pp++) { accA[pp] = 0.f; accB[pp] = 0.f; }
    for (int tile = 0; tile < 16; tile++) {
      const int c0 = tile * 16;
      {
        const int orow = t >> 2, qq = t & 3;
#pragma unroll
        for (int pass = 0; pass < 4; pass++) {
          int oo = orow + pass * 64;
          *(float4*)&Wt[oo * 20 + qq * 4] =
              *(const float4*)(w + oo * 256 + c0 + qq * 4);
        }
      }
      __syncthreads();
#pragma unroll
      for (int j4 = 0; j4 < 4; j4++) {
        const float4 wa = *(const float4*)&Wt[oA * 20 + j4 * 4];
        const float4 wb = *(const float4*)&Wt[oB * 20 + j4 * 4];
#pragma unroll
        for (int pp = 0; pp < 8; pp++) {
          const float4 xv =
              *(const float4*)&inb[(pB + pp) * PHST + c0 + j4 * 4];
          accA[pp] = fmaf(wa.x, xv.x, accA[pp]);
          accA[pp] = fmaf(wa.y, xv.y, accA[pp]);
          accA[pp] = fmaf(wa.z, xv.z, accA[pp]);
          accA[pp] = fmaf(wa.w, xv.w, accA[pp]);
          accB[pp] = fmaf(wb.x, xv.x, accB[pp]);
          accB[pp] = fmaf(wb.y, xv.y, accB[pp]);
          accB[pp] = fmaf(wb.z, xv.z, accB[pp]);
          accB[pp] = fmaf(wb.w, xv.w, accB[pp]);
        }
      }
      __syncthreads();
    }
    const float sA = pg[l * 256 + oA] / sqrtf(pv[l * 256 + oA] + 1e-5f);
    const float sB = pg[l * 256 + oB] / sqrtf(pv[l * 256 + oB] + 1e-5f);
    const float mA = pm[l * 256 + oA], mB = pm[l * 256 + oB];
    const float bA = pb[l * 256 + oA], bB = pb[l * 256 + oB];
#pragma unroll
    for (int pp = 0; pp < 8; pp++) {
      outb[(pB + pp) * PHST + oA] = fmaxf((accA[pp] - mA) * sA + bA, 0.f);
      outb[(pB + pp) * PHST + oB] = fmaxf((accB[pp] - mB) * sB + bB, 0.f);
    }
  }
  // final layer: 119 outputs, reads Yt
  {
    const int o = t & 127, ph = t >> 7;
    float a3[8];
#pragma unroll
    for (int pp = 0; pp < 8; pp++) a3[pp] = 0.f;
    for (int tile = 0; tile < 16; tile++) {
      const int c0 = tile * 16;
      for (int u = t; u < 119 * 4; u += 256) {
        int oo = u >> 2, qq = u & 3;
        *(float4*)&Wt[oo * 20 + qq * 4] =
            *(const float4*)(pw3 + oo * 256 + c0 + qq * 4);
      }
      __syncthreads();
      if (o < 119) {
#pragma unroll
        for (int j4 = 0; j4 < 4; j4++) {
          const float4 wv = *(const float4*)&Wt[o * 20 + j4 * 4];
#pragma unroll
          for (int pp = 0; pp < 8; pp++) {
            const float4 xv =
                *(const float4*)&Yt[(ph * 8 + pp) * PHST + c0 + j4 * 4];
            a3[pp] = fmaf(wv.x, xv.x, a3[pp]);
            a3[pp] = fmaf(wv.y, xv.y, a3[pp]);
            a3[pp] = fmaf(wv.z, xv.z, a3[pp]);
            a3[pp] = fmaf(wv.w, xv.w, a3[pp]);
          }
        }
      }
      __syncthreads();
    }
    if (o < 119) {
      const float bb = pb3[o];
#pragma unroll
      for (int pp = 0; pp < 8; pp++) net_s[(ph * 8 + pp) * 120 + o] = a3[pp] + bb;
    }
  }
  __syncthreads();

  if (t < 16) {
    const int pg_i = p0 + t;
    const int gi = b * P_ + pg_i;
    const float* nr = &net_s[t * 120];
    const float nx = new_xyz[gi * 3 + 0];
    const float ny = new_xyz[gi * 3 + 1];
    const float nz = new_xyz[gi * 3 + 2];
    const float obj0 = nr[0], obj1 = nr[1];
    out[OFF0 + gi * 2 + 0] = obj0;
    out[OFF0 + gi * 2 + 1] = obj1;
    const float cx = nx + nr[2], cy = ny + nr[3], cz = nz + nr[4];
    out[OFF1 + gi * 3 + 0] = cx;
    out[OFF1 + gi * 3 + 1] = cy;
    out[OFF1 + gi * 3 + 2] = cz;
    float bv = -1e30f;
    int bi = 0;
#pragma unroll
    for (int i = 0; i < 18; i++) {
      float v = nr[29 + i];
      out[OFF2 + gi * 18 + i] = v;
      if (v > bv) { bv = v; bi = i; }
    }
#pragma unroll
    for (int i = 0; i < 18; i++)
#pragma unroll
      for (int j = 0; j < 3; j++)
        out[OFF3 + gi * 54 + i * 3 + j] =
            __fmul_rn(nr[47 + i * 3 + j], msa[i * 3 + j]);
    float ps[3];
#pragma unroll
    for (int j = 0; j < 3; j++) {
      ps[j] = __fadd_rn(__fmul_rn(nr[47 + bi * 3 + j], msa[bi * 3 + j]),
                        msa[bi * 3 + j]);
      out[OFF4 + gi * 3 + j] = ps[j];
    }
    float sm = -1e30f;
#pragma unroll
    for (int i = 0; i < 18; i++) {
      float v = nr[101 + i];
      out[OFF5 + gi * 18 + i] = v;
      out[OFF7 + gi * 19 + i] = v;
      sm = fmaxf(sm, v);
    }
    out[OFF7 + gi * 19 + 18] = (obj0 <= obj1) ? 0.f : 1e10f;
    const float cc0 = cx, cc1 = cz, cc2 = -cy;
    const float sxk[8] = {1, 1, -1, -1, 1, 1, -1, -1};
    const float syk[8] = {1, 1, 1, 1, -1, -1, -1, -1};
    const float szk[8] = {1, -1, -1, 1, 1, -1, -1, 1};
#pragma unroll
    for (int k = 0; k < 8; k++) {
      out[OFF6 + gi * 24 + 3 * k + 0] = cc0 + ps[0] * sxk[k] * 0.5f;
      out[OFF6 + gi * 24 + 3 * k + 1] = cc1 + ps[2] * syk[k] * 0.5f;
      out[OFF6 + gi * 24 + 3 * k + 2] = cc2 + ps[1] * szk[k] * 0.5f;
    }
    {
      const float m2 = fmaxf(obj0, obj1);
      const float e0 = expf(obj0 - m2), e1 = expf(obj1 - m2);
      out[OFF8 + gi] = e1 / (e0 + e1);
    }
    {
      float ev[18], es = 0.f;
#pragma unroll
      for (int i = 0; i < 18; i++) {
        ev[i] = expf(nr[101 + i] - sm);
        es += ev[i];
      }
#pragma unroll
      for (int i = 0; i < 18; i++) out[OFF9 + gi * 18 + i] = ev[i] / es;
    }
  }
}

// ---------------------------------------------------------------------------
extern "C" void kernel_launch(void* const* d_in, const int* in_sizes, int n_in,
                              void* d_out, int out_size, void* d_ws,
                              size_t ws_size, hipStream_t stream) {
  (void)in_sizes; (void)n_in; (void)out_size; (void)ws_size;
  const float* xyz      = (const float*)d_in[0];
  const float* features = (const float*)d_in[1];
  const float* w1       = (const float*)d_in[2];
  const float* w2       = (const float*)d_in[3];
  const float* w3       = (const float*)d_in[4];
  const float* gma      = (const float*)d_in[5];
  const float* bta      = (const float*)d_in[6];
  const float* mu       = (const float*)d_in[7];
  const float* var      = (const float*)d_in[8];
  const float* pw1      = (const float*)d_in[9];
  const float* pw2      = (const float*)d_in[10];
  const float* pw3      = (const float*)d_in[11];
  const float* pb3      = (const float*)d_in[12];
  const float* pg       = (const float*)d_in[13];
  const float* pb       = (const float*)d_in[14];
  const float* pm       = (const float*)d_in[15];
  const float* pv       = (const float*)d_in[16];
  const float* msa      = (const float*)d_in[17];
  float* out = (float*)d_out;

  char* ws = (char*)d_ws;
  float*     new_xyz = (float*)ws;                  // 98304 B
  int*       idxw    = (int*)(ws + 98304);          // 524288 B
  float*     yb      = (float*)(ws + 622592);       // 8388608 B
  _Float16*  w1h     = (_Float16*)(ws + 9011200);   // 147456 B
  _Float16*  w1l     = (_Float16*)(ws + 9158656);   // 147456 B
  _Float16*  w2h     = (_Float16*)(ws + 9306112);   // 131072 B
  _Float16*  w2l     = (_Float16*)(ws + 9437184);   // 131072 B
  _Float16*  w3h     = (_Float16*)(ws + 9568256);   // 131072 B
  _Float16*  w3l     = (_Float16*)(ws + 9699328);   // 131072 B
  float*     bns     = (float*)(ws + 9830400);      // 3072 B

  wsplit_kernel<<<401, 64, 0, stream>>>(w1, w2, w3, gma, var, w1h, w1l, w2h,
                                        w2l, w3h, w3l, bns);
  fps_kernel<<<B_, 256, 0, stream>>>(xyz, new_xyz);
  ballq_kernel<<<B_, 256, 0, stream>>>(xyz, new_xyz, idxw);
  sa_kernel<<<B_ * 128, 256, 0, stream>>>(xyz, features, w1h, w1l, w2h, w2l,
                                          w3h, w3l, bns, mu, bta, new_xyz,
                                          idxw, yb);
  phead_kernel<<<B_ * 16, 256, 0, stream>>>(yb, pw1, pw2, pw3, pb3, pg, pb, pm,
                                            pv, new_xyz, msa, out);
}

// Round 7
// 806.611 us; speedup vs baseline: 1.7623x; 1.1209x over previous
//
#include <hip/hip_runtime.h>
#include <math.h>

#define B_   32
#define K_   2048
#define C_   256
#define P_   256
#define S_   16
#define OUTC 119

// output offsets (floats)
#define OFF0 0        // obj        (B,P,2)
#define OFF1 16384    // center     (B,P,3)
#define OFF2 40960    // size_scores(B,P,18)
#define OFF3 188416   // size_res   (B,P,18,3)
#define OFF4 630784   // pred_size  (B,P,3)
#define OFF5 655360   // sem        (B,P,18)
#define OFF6 802816   // corners    (B,P,8,3)
#define OFF7 999424   // sem_logits (B,P,19)
#define OFF8 1155072  // obj_prob   (B,P)
#define OFF9 1163264  // sem_prob   (B,P,18)

typedef _Float16 half8  __attribute__((ext_vector_type(8)));
typedef _Float16 half4h __attribute__((ext_vector_type(4)));
typedef float    f32x4  __attribute__((ext_vector_type(4)));
#define MFMA16 __builtin_amdgcn_mfma_f32_16x16x32_f16

__device__ __forceinline__ float sqdist_rn(float ax, float ay, float az,
                                           float bx, float by, float bz) {
  float dx = __fsub_rn(ax, bx), dy = __fsub_rn(ay, by), dz = __fsub_rn(az, bz);
  return __fadd_rn(__fadd_rn(__fmul_rn(dx, dx), __fmul_rn(dy, dy)),
                   __fmul_rn(dz, dz));
}

// ------------------------------------------- weight split to f16 hi/lo -----
// (sa weights only — phead stays f32: its argmin(obj) head cannot tolerate
// f16-split perturbation, measured round 6.)
__global__ __launch_bounds__(64) void wsplit_kernel(
    const float* __restrict__ w1, const float* __restrict__ w2,
    const float* __restrict__ w3, const float* __restrict__ gma,
    const float* __restrict__ var, _Float16* __restrict__ w1h,
    _Float16* __restrict__ w1l, _Float16* __restrict__ w2h,
    _Float16* __restrict__ w2l, _Float16* __restrict__ w3h,
    _Float16* __restrict__ w3l, float* __restrict__ bns) {
  const int r = blockIdx.x, t = threadIdx.x;
  if (r == 400) {
    for (int u = t; u < 768; u += 64) bns[u] = gma[u] / sqrtf(var[u] + 1e-5f);
    return;
  }
  const float* src;
  _Float16 *dh, *dl;
  int ot, ks, nks, K;
  if (r < 144) {
    src = w1; dh = w1h; dl = w1l; ot = r / 9; ks = r % 9; nks = 9; K = 259;
  } else if (r < 272) {
    const int rr = r - 144;
    src = w2; dh = w2h; dl = w2l; ot = rr >> 3; ks = rr & 7; nks = 8; K = 256;
  } else {
    const int rr = r - 272;
    src = w3; dh = w3h; dl = w3l; ot = rr >> 3; ks = rr & 7; nks = 8; K = 256;
  }
  const int m = t & 15, q = t >> 4;
  const float* row = src + (ot * 16 + m) * K;
  half8 vh, vl;
#pragma unroll
  for (int j = 0; j < 8; j++) {
    const int c = ks * 32 + q * 8 + j;
    const float v = (c < K) ? row[c] : 0.f;
    const _Float16 hi = (_Float16)v;
    vh[j] = hi;
    vl[j] = (_Float16)(v - (float)hi);
  }
  const int base = ((ot * nks + ks) * 64 + t) * 8;
  *(half8*)&dh[base] = vh;
  *(half8*)&dl[base] = vl;
}

// ---------------------------------------------------------------- FPS ------
// One wave per batch, all-register, barrier-free (validated bit-exact in
// round 6: all index-dependent outputs passed). Butterfly on packed u64 key
// (dist_bits<<32)|~k: u64-max == (max dist, tie -> lowest k) == numpy
// first-occurrence argmax, bit-exact.
__global__ __launch_bounds__(64) void fps_kernel(const float* __restrict__ xyz,
                                                 float* __restrict__ new_xyz) {
  const int b = blockIdx.x, lane = threadIdx.x;
  const float* xb = xyz + b * K_ * 3;
  __shared__ __align__(16) float4 pts[K_];  // 32 KB
  float px[32], py[32], pz[32], dist[32];
#pragma unroll
  for (int j = 0; j < 32; j++) {
    const int k = lane + 64 * j;
    const float x = xb[3 * k + 0];
    const float yv = xb[3 * k + 1];
    const float z = xb[3 * k + 2];
    px[j] = x; py[j] = yv; pz[j] = z;
    dist[j] = 1e10f;
    pts[k] = make_float4(x, yv, z, 0.f);
  }
  __syncthreads();
  int far = 0;
  for (int i = 0; i < P_; i++) {
    const float4 c = pts[far];  // uniform address -> LDS broadcast
    if (lane == 0) {
      float* nx = new_xyz + (b * P_ + i) * 3;
      nx[0] = c.x; nx[1] = c.y; nx[2] = c.z;
    }
    float bv = -1.f;
    int bj = 0;
#pragma unroll
    for (int j = 0; j < 32; j++) {
      const float d = sqdist_rn(px[j], py[j], pz[j], c.x, c.y, c.z);
      dist[j] = fminf(dist[j], d);
      if (dist[j] > bv) { bv = dist[j]; bj = j; }  // strict > keeps lowest j
    }
    const unsigned kg = (unsigned)(bj * 64 + lane);
    unsigned long long key =
        ((unsigned long long)__float_as_uint(bv) << 32) |
        (unsigned long long)(0xFFFFFFFFu - kg);
#pragma unroll
    for (int off = 1; off < 64; off <<= 1) {
      const unsigned long long o = __shfl_xor(key, off);
      key = (o > key) ? o : key;
    }
    far = (int)(0xFFFFFFFFu - (unsigned)(key & 0xFFFFFFFFull));
  }
}

// ---------------------------------------------------------- ball query -----
__global__ __launch_bounds__(256) void ballq_kernel(const float* __restrict__ xyz,
                                                    const float* __restrict__ new_xyz,
                                                    int* __restrict__ idxw) {
  const int b = blockIdx.x, t = threadIdx.x;
  __shared__ __align__(16) float pts[K_ * 4];
  const float* xb = xyz + b * K_ * 3;
#pragma unroll
  for (int j = 0; j < 8; j++) {
    int k = t + 256 * j;
    pts[4 * k + 0] = xb[3 * k + 0];
    pts[4 * k + 1] = xb[3 * k + 1];
    pts[4 * k + 2] = xb[3 * k + 2];
    pts[4 * k + 3] = 0.f;
  }
  __syncthreads();
  const float r2 = (float)(0.3 * 0.3);
  const int p = t;
  const float nx = new_xyz[(b * P_ + p) * 3 + 0];
  const float ny = new_xyz[(b * P_ + p) * 3 + 1];
  const float nz = new_xyz[(b * P_ + p) * 3 + 2];
  int* ob = idxw + (b * P_ + p) * S_;
  int cnt = 0, first = 0;
  for (int k = 0; k < K_; k++) {
    if (cnt >= S_) break;
    const float4 q = *(const float4*)&pts[4 * k];
    float d2 = sqdist_rn(q.x, q.y, q.z, nx, ny, nz);
    if (d2 < r2) {
      if (cnt == 0) first = k;
      ob[cnt] = k;
      cnt++;
    }
  }
  for (int s = cnt; s < S_; s++) ob[s] = first;
}

// ------------------------------------------------------------- SA MLP ------
// Split-f16 MFMA: D = Wh*Xh + Wh*Xl + Wl*Xh (error ~2^-22). 2 proposals
// (32 samples)/block, 4 waves; wave w: o-tiles 4w..4w+3, both s-tiles.
__global__ __launch_bounds__(256, 2) void sa_kernel(
    const float* __restrict__ xyz, const float* __restrict__ features,
    const _Float16* __restrict__ w1h, const _Float16* __restrict__ w1l,
    const _Float16* __restrict__ w2h, const _Float16* __restrict__ w2l,
    const _Float16* __restrict__ w3h, const _Float16* __restrict__ w3l,
    const float* __restrict__ bns, const float* __restrict__ mu,
    const float* __restrict__ bta, const float* __restrict__ new_xyz,
    const int* __restrict__ idxw, float* __restrict__ y) {
  const int blk = blockIdx.x;  // 4096
  const int b = blk >> 7, p0 = (blk & 127) * 2, t = threadIdx.x;
  __shared__ __align__(16) _Float16 X1h[32 * 296];
  __shared__ __align__(16) _Float16 X1l[32 * 296];
  __shared__ __align__(16) _Float16 X2h[32 * 264];
  __shared__ __align__(16) _Float16 X2l[32 * 264];
  __shared__ __align__(16) float red[2 * 256];
  __shared__ int k_sh[32];

  if (t < 32) k_sh[t] = idxw[(b * P_ + p0) * S_ + t];
  for (int u = t; u < 32 * 32; u += 256) {
    const int s = u >> 5, cc = 256 + (u & 31);
    if (cc >= 259) {
      X1h[s * 296 + cc] = (_Float16)0.f;
      X1l[s * 296 + cc] = (_Float16)0.f;
    }
  }
  __syncthreads();
  if (t < 32) {
    const int pl = t >> 4, k = k_sh[t];
    const float* xb = xyz + b * K_ * 3;
    const float* nx = new_xyz + (b * P_ + p0 + pl) * 3;
#pragma unroll
    for (int c = 0; c < 3; c++) {
      const float v = (xb[3 * k + c] - nx[c]) / 0.3f;
      const _Float16 hi = (_Float16)v;
      X1h[t * 296 + c] = hi;
      X1l[t * 296 + c] = (_Float16)(v - (float)hi);
    }
  }
  {
    const float* fb = features + (size_t)b * C_ * K_ + (size_t)t * K_;
    const int c = 3 + t;
#pragma unroll 8
    for (int s = 0; s < 32; s++) {
      const float v = fb[k_sh[s]];
      const _Float16 hi = (_Float16)v;
      X1h[s * 296 + c] = hi;
      X1l[s * 296 + c] = (_Float16)(v - (float)hi);
    }
  }

  const int lane = t & 63, w = t >> 6;
  const int m = lane & 15, q = lane >> 4;

  f32x4 acc[4][2];
  half8 pAh[4], pAl[4];
#pragma unroll
  for (int i = 0; i < 4; i++) {
    const int off = (((4 * w + i) * 9) * 64 + lane) * 8;
    pAh[i] = *(const half8*)&w1h[off];
    pAl[i] = *(const half8*)&w1l[off];
  }
  __syncthreads();

#pragma unroll
  for (int l = 0; l < 3; l++) {
    const _Float16* Xih = (l == 1) ? X2h : X1h;
    const _Float16* Xil = (l == 1) ? X2l : X1l;
    const int XS = (l == 1) ? 264 : 296;
    const int nks = (l == 0) ? 9 : 8;
#pragma unroll
    for (int i = 0; i < 4; i++) {
      acc[i][0] = (f32x4){0.f, 0.f, 0.f, 0.f};
      acc[i][1] = (f32x4){0.f, 0.f, 0.f, 0.f};
    }
    for (int ks = 0; ks < nks; ks++) {
      half8 Ah[4], Al[4];
#pragma unroll
      for (int i = 0; i < 4; i++) { Ah[i] = pAh[i]; Al[i] = pAl[i]; }
      {
        int ln = l, kn = ks + 1;
        if (kn == nks) { ln = l + 1; kn = 0; }
        if (ln < 3) {
          const _Float16* Ph = (ln == 0) ? w1h : (ln == 1) ? w2h : w3h;
          const _Float16* Pl = (ln == 0) ? w1l : (ln == 1) ? w2l : w3l;
          const int nk2 = (ln == 0) ? 9 : 8;
#pragma unroll
          for (int i = 0; i < 4; i++) {
            const int off = (((4 * w + i) * nk2 + kn) * 64 + lane) * 8;
            pAh[i] = *(const half8*)&Ph[off];
            pAl[i] = *(const half8*)&Pl[off];
          }
        }
      }
      const int xo = ks * 32 + q * 8;
      const half8 Bh0 = *(const half8*)&Xih[m * XS + xo];
      const half8 Bl0 = *(const half8*)&Xil[m * XS + xo];
      const half8 Bh1 = *(const half8*)&Xih[(16 + m) * XS + xo];
      const half8 Bl1 = *(const half8*)&Xil[(16 + m) * XS + xo];
#pragma unroll
      for (int i = 0; i < 4; i++) {
        acc[i][0] = MFMA16(Ah[i], Bh0, acc[i][0], 0, 0, 0);
        acc[i][0] = MFMA16(Ah[i], Bl0, acc[i][0], 0, 0, 0);
        acc[i][0] = MFMA16(Al[i], Bh0, acc[i][0], 0, 0, 0);
        acc[i][1] = MFMA16(Ah[i], Bh1, acc[i][1], 0, 0, 0);
        acc[i][1] = MFMA16(Ah[i], Bl1, acc[i][1], 0, 0, 0);
        acc[i][1] = MFMA16(Al[i], Bh1, acc[i][1], 0, 0, 0);
      }
    }

    if (l < 2) {
      _Float16* Xoh = (l == 0) ? X2h : X1h;
      _Float16* Xol = (l == 0) ? X2l : X1l;
      const int XSo = (l == 0) ? 264 : 296;
#pragma unroll
      for (int i = 0; i < 4; i++) {
        const int ob = (4 * w + i) * 16 + q * 4;
        const f32x4 sc4 = *(const f32x4*)&bns[l * 256 + ob];
        const f32x4 m4 = *(const f32x4*)&mu[l * 256 + ob];
        const f32x4 b4 = *(const f32x4*)&bta[l * 256 + ob];
#pragma unroll
        for (int s = 0; s < 2; s++) {
          half4h vh, vl;
#pragma unroll
          for (int r = 0; r < 4; r++) {
            const float v = fmaxf((acc[i][s][r] - m4[r]) * sc4[r] + b4[r], 0.f);
            const _Float16 hi = (_Float16)v;
            vh[r] = hi;
            vl[r] = (_Float16)(v - (float)hi);
          }
          const int scol = s * 16 + m;
          *(half4h*)&Xoh[scol * XSo + ob] = vh;
          *(half4h*)&Xol[scol * XSo + ob] = vl;
        }
      }
      __syncthreads();
    } else {
#pragma unroll
      for (int i = 0; i < 4; i++)
#pragma unroll
        for (int s = 0; s < 2; s++)
#pragma unroll
          for (int r = 0; r < 4; r++) {
            float v = acc[i][s][r];
            v = fmaxf(v, __shfl_xor(v, 1));
            v = fmaxf(v, __shfl_xor(v, 2));
            v = fmaxf(v, __shfl_xor(v, 4));
            v = fmaxf(v, __shfl_xor(v, 8));
            acc[i][s][r] = v;
          }
      if (m == 0) {
#pragma unroll
        for (int i = 0; i < 4; i++) {
          const int ob = (4 * w + i) * 16 + q * 4;
          *(f32x4*)&red[ob] = acc[i][0];
          *(f32x4*)&red[256 + ob] = acc[i][1];
        }
      }
      __syncthreads();
      const float sc2 = bns[512 + t];
      const float mu2 = mu[512 + t], bt2 = bta[512 + t];
#pragma unroll
      for (int pl = 0; pl < 2; pl++) {
        const float raw = red[pl * 256 + t];
        y[(b * P_ + p0 + pl) * 256 + t] = fmaxf((raw - mu2) * sc2 + bt2, 0.f);
      }
    }
  }
}

// ------------------------------------------------- P-layers + all heads ----
// f32 (round-5 known-good): argmin(obj) head pins this GEMM to f32 accuracy.
#define PHST 260
__global__ __launch_bounds__(256, 2) void phead_kernel(
    const float* __restrict__ y, const float* __restrict__ pw1,
    const float* __restrict__ pw2, const float* __restrict__ pw3,
    const float* __restrict__ pb3, const float* __restrict__ pg,
    const float* __restrict__ pb, const float* __restrict__ pm,
    const float* __restrict__ pv, const float* __restrict__ new_xyz,
    const float* __restrict__ msa, float* __restrict__ out) {
  const int blk = blockIdx.x;
  const int b = blk >> 4, p0 = (blk & 15) * 16, t = threadIdx.x;
  __shared__ __align__(16) float Yt[16 * PHST];
  __shared__ __align__(16) float Ht[16 * PHST];
  __shared__ __align__(16) float Wt[256 * 20];
  __shared__ float net_s[16 * 120];

  for (int u = t; u < 16 * 256; u += 256) {
    int pl = u >> 8, c = u & 255;
    Yt[pl * PHST + c] = y[(b * P_ + p0 + pl) * C_ + c];
  }
  __syncthreads();

  const int oA = t & 127, oB = oA + 128, pB = (t >> 7) * 8;
  float accA[8], accB[8];
  for (int l = 0; l < 2; l++) {
    const float* w = l ? pw2 : pw1;
    const float* inb = l ? Ht : Yt;
    float* outb = l ? Yt : Ht;
#pragma unroll
    for (int pp = 0; pp < 8; pp++) { accA[pp] = 0.f; accB[pp] = 0.f; }
    for (int tile = 0; tile < 16; tile++) {
      const int c0 = tile * 16;
      {
        const int orow = t >> 2, qq = t & 3;
#pragma unroll
        for (int pass = 0; pass < 4; pass++) {
          int oo = orow + pass * 64;
          *(float4*)&Wt[oo * 20 + qq * 4] =
              *(const float4*)(w + oo * 256 + c0 + qq * 4);
        }
      }
      __syncthreads();
#pragma unroll
      for (int j4 = 0; j4 < 4; j4++) {
        const float4 wa = *(const float4*)&Wt[oA * 20 + j4 * 4];
        const float4 wb = *(const float4*)&Wt[oB * 20 + j4 * 4];
#pragma unroll
        for (int pp = 0; pp < 8; pp++) {
          const float4 xv =
              *(const float4*)&inb[(pB + pp) * PHST + c0 + j4 * 4];
          accA[pp] = fmaf(wa.x, xv.x, accA[pp]);
          accA[pp] = fmaf(wa.y, xv.y, accA[pp]);
          accA[pp] = fmaf(wa.z, xv.z, accA[pp]);
          accA[pp] = fmaf(wa.w, xv.w, accA[pp]);
          accB[pp] = fmaf(wb.x, xv.x, accB[pp]);
          accB[pp] = fmaf(wb.y, xv.y, accB[pp]);
          accB[pp] = fmaf(wb.z, xv.z, accB[pp]);
          accB[pp] = fmaf(wb.w, xv.w, accB[pp]);
        }
      }
      __syncthreads();
    }
    const float sA = pg[l * 256 + oA] / sqrtf(pv[l * 256 + oA] + 1e-5f);
    const float sB = pg[l * 256 + oB] / sqrtf(pv[l * 256 + oB] + 1e-5f);
    const float mA = pm[l * 256 + oA], mB = pm[l * 256 + oB];
    const float bA = pb[l * 256 + oA], bB = pb[l * 256 + oB];
#pragma unroll
    for (int pp = 0; pp < 8; pp++) {
      outb[(pB + pp) * PHST + oA] = fmaxf((accA[pp] - mA) * sA + bA, 0.f);
      outb[(pB + pp) * PHST + oB] = fmaxf((accB[pp] - mB) * sB + bB, 0.f);
    }
  }
  // final layer: 119 outputs, reads Yt
  {
    const int o = t & 127, ph = t >> 7;
    float a3[8];
#pragma unroll
    for (int pp = 0; pp < 8; pp++) a3[pp] = 0.f;
    for (int tile = 0; tile < 16; tile++) {
      const int c0 = tile * 16;
      for (int u = t; u < 119 * 4; u += 256) {
        int oo = u >> 2, qq = u & 3;
        *(float4*)&Wt[oo * 20 + qq * 4] =
            *(const float4*)(pw3 + oo * 256 + c0 + qq * 4);
      }
      __syncthreads();
      if (o < 119) {
#pragma unroll
        for (int j4 = 0; j4 < 4; j4++) {
          const float4 wv = *(const float4*)&Wt[o * 20 + j4 * 4];
#pragma unroll
          for (int pp = 0; pp < 8; pp++) {
            const float4 xv =
                *(const float4*)&Yt[(ph * 8 + pp) * PHST + c0 + j4 * 4];
            a3[pp] = fmaf(wv.x, xv.x, a3[pp]);
            a3[pp] = fmaf(wv.y, xv.y, a3[pp]);
            a3[pp] = fmaf(wv.z, xv.z, a3[pp]);
            a3[pp] = fmaf(wv.w, xv.w, a3[pp]);
          }
        }
      }
      __syncthreads();
    }
    if (o < 119) {
      const float bb = pb3[o];
#pragma unroll
      for (int pp = 0; pp < 8; pp++) net_s[(ph * 8 + pp) * 120 + o] = a3[pp] + bb;
    }
  }
  __syncthreads();

  if (t < 16) {
    const int pg_i = p0 + t;
    const int gi = b * P_ + pg_i;
    const float* nr = &net_s[t * 120];
    const float nx = new_xyz[gi * 3 + 0];
    const float ny = new_xyz[gi * 3 + 1];
    const float nz = new_xyz[gi * 3 + 2];
    const float obj0 = nr[0], obj1 = nr[1];
    out[OFF0 + gi * 2 + 0] = obj0;
    out[OFF0 + gi * 2 + 1] = obj1;
    const float cx = nx + nr[2], cy = ny + nr[3], cz = nz + nr[4];
    out[OFF1 + gi * 3 + 0] = cx;
    out[OFF1 + gi * 3 + 1] = cy;
    out[OFF1 + gi * 3 + 2] = cz;
    float bv = -1e30f;
    int bi = 0;
#pragma unroll
    for (int i = 0; i < 18; i++) {
      float v = nr[29 + i];
      out[OFF2 + gi * 18 + i] = v;
      if (v > bv) { bv = v; bi = i; }
    }
#pragma unroll
    for (int i = 0; i < 18; i++)
#pragma unroll
      for (int j = 0; j < 3; j++)
        out[OFF3 + gi * 54 + i * 3 + j] =
            __fmul_rn(nr[47 + i * 3 + j], msa[i * 3 + j]);
    float ps[3];
#pragma unroll
    for (int j = 0; j < 3; j++) {
      ps[j] = __fadd_rn(__fmul_rn(nr[47 + bi * 3 + j], msa[bi * 3 + j]),
                        msa[bi * 3 + j]);
      out[OFF4 + gi * 3 + j] = ps[j];
    }
    float sm = -1e30f;
#pragma unroll
    for (int i = 0; i < 18; i++) {
      float v = nr[101 + i];
      out[OFF5 + gi * 18 + i] = v;
      out[OFF7 + gi * 19 + i] = v;
      sm = fmaxf(sm, v);
    }
    out[OFF7 + gi * 19 + 18] = (obj0 <= obj1) ? 0.f : 1e10f;
    const float cc0 = cx, cc1 = cz, cc2 = -cy;
    const float sxk[8] = {1, 1, -1, -1, 1, 1, -1, -1};
    const float syk[8] = {1, 1, 1, 1, -1, -1, -1, -1};
    const float szk[8] = {1, -1, -1, 1, 1, -1, -1, 1};
#pragma unroll
    for (int k = 0; k < 8; k++) {
      out[OFF6 + gi * 24 + 3 * k + 0] = cc0 + ps[0] * sxk[k] * 0.5f;
      out[OFF6 + gi * 24 + 3 * k + 1] = cc1 + ps[2] * syk[k] * 0.5f;
      out[OFF6 + gi * 24 + 3 * k + 2] = cc2 + ps[1] * szk[k] * 0.5f;
    }
    {
      const float m2 = fmaxf(obj0, obj1);
      const float e0 = expf(obj0 - m2), e1 = expf(obj1 - m2);
      out[OFF8 + gi] = e1 / (e0 + e1);
    }
    {
      float ev[18], es = 0.f;
#pragma unroll
      for (int i = 0; i < 18; i++) {
        ev[i] = expf(nr[101 + i] - sm);
        es += ev[i];
      }
#pragma unroll
      for (int i = 0; i < 18; i++) out[OFF9 + gi * 18 + i] = ev[i] / es;
    }
  }
}

// ---------------------------------------------------------------------------
extern "C" void kernel_launch(void* const* d_in, const int* in_sizes, int n_in,
                              void* d_out, int out_size, void* d_ws,
                              size_t ws_size, hipStream_t stream) {
  (void)in_sizes; (void)n_in; (void)out_size; (void)ws_size;
  const float* xyz      = (const float*)d_in[0];
  const float* features = (const float*)d_in[1];
  const float* w1       = (const float*)d_in[2];
  const float* w2       = (const float*)d_in[3];
  const float* w3       = (const float*)d_in[4];
  const float* gma      = (const float*)d_in[5];
  const float* bta      = (const float*)d_in[6];
  const float* mu       = (const float*)d_in[7];
  const float* var      = (const float*)d_in[8];
  const float* pw1      = (const float*)d_in[9];
  const float* pw2      = (const float*)d_in[10];
  const float* pw3      = (const float*)d_in[11];
  const float* pb3      = (const float*)d_in[12];
  const float* pg       = (const float*)d_in[13];
  const float* pb       = (const float*)d_in[14];
  const float* pm       = (const float*)d_in[15];
  const float* pv       = (const float*)d_in[16];
  const float* msa      = (const float*)d_in[17];
  float* out = (float*)d_out;

  char* ws = (char*)d_ws;
  float*     new_xyz = (float*)ws;                   // 98304 B
  int*       idxw    = (int*)(ws + 98304);           // 524288 B
  float*     yb      = (float*)(ws + 622592);        // 8388608 B
  _Float16*  w1h     = (_Float16*)(ws + 9011200);    // 147456 B
  _Float16*  w1l     = (_Float16*)(ws + 9158656);    // 147456 B
  _Float16*  w2h     = (_Float16*)(ws + 9306112);    // 131072 B
  _Float16*  w2l     = (_Float16*)(ws + 9437184);    // 131072 B
  _Float16*  w3h     = (_Float16*)(ws + 9568256);    // 131072 B
  _Float16*  w3l     = (_Float16*)(ws + 9699328);    // 131072 B
  float*     bns     = (float*)(ws + 9830400);       // 3072 B

  wsplit_kernel<<<401, 64, 0, stream>>>(w1, w2, w3, gma, var, w1h, w1l, w2h,
                                        w2l, w3h, w3l, bns);
  fps_kernel<<<B_, 64, 0, stream>>>(xyz, new_xyz);
  ballq_kernel<<<B_, 256, 0, stream>>>(xyz, new_xyz, idxw);
  sa_kernel<<<B_ * 128, 256, 0, stream>>>(xyz, features, w1h, w1l, w2h, w2l,
                                          w3h, w3l, bns, mu, bta, new_xyz,
                                          idxw, yb);
  phead_kernel<<<B_ * 16, 256, 0, stream>>>(yb, pw1, pw2, pw3, pb3, pg, pb, pm,
                                            pv, new_xyz, msa, out);
}

// Round 8
// 783.861 us; speedup vs baseline: 1.8135x; 1.0290x over previous
//
#include <hip/hip_runtime.h>
#include <math.h>

#define B_   32
#define K_   2048
#define C_   256
#define P_   256
#define S_   16
#define OUTC 119

// output offsets (floats)
#define OFF0 0        // obj        (B,P,2)
#define OFF1 16384    // center     (B,P,3)
#define OFF2 40960    // size_scores(B,P,18)
#define OFF3 188416   // size_res   (B,P,18,3)
#define OFF4 630784   // pred_size  (B,P,3)
#define OFF5 655360   // sem        (B,P,18)
#define OFF6 802816   // corners    (B,P,8,3)
#define OFF7 999424   // sem_logits (B,P,19)
#define OFF8 1155072  // obj_prob   (B,P)
#define OFF9 1163264  // sem_prob   (B,P,18)

typedef _Float16 half8  __attribute__((ext_vector_type(8)));
typedef _Float16 half4h __attribute__((ext_vector_type(4)));
typedef float    f32x4  __attribute__((ext_vector_type(4)));
#define MFMA16 __builtin_amdgcn_mfma_f32_16x16x32_f16

__device__ __forceinline__ float sqdist_rn(float ax, float ay, float az,
                                           float bx, float by, float bz) {
  float dx = __fsub_rn(ax, bx), dy = __fsub_rn(ay, by), dz = __fsub_rn(az, bz);
  return __fadd_rn(__fadd_rn(__fmul_rn(dx, dx), __fmul_rn(dy, dy)),
                   __fmul_rn(dz, dz));
}

// ------------------------------------------- weight split to f16 hi/lo -----
// Fragment-order layout: Wf[tile = ot*nks + ks][lane][8] -> A-frag load is
// one coalesced 1KB wave read. sa l0 padded K 259->288 (9 k-steps).
// Blocks: 0..143 w1, 144..271 w2, 272..399 w3, 400..527 pw1, 528..655 pw2,
// 656: BN scale prep (sa 768 + p-layers 512). pw3 stays f32 (l2 exact).
__global__ __launch_bounds__(64) void wsplit_kernel(
    const float* __restrict__ w1, const float* __restrict__ w2,
    const float* __restrict__ w3, const float* __restrict__ pw1,
    const float* __restrict__ pw2, const float* __restrict__ gma,
    const float* __restrict__ var, const float* __restrict__ pg,
    const float* __restrict__ pv, _Float16* __restrict__ w1h,
    _Float16* __restrict__ w1l, _Float16* __restrict__ w2h,
    _Float16* __restrict__ w2l, _Float16* __restrict__ w3h,
    _Float16* __restrict__ w3l, _Float16* __restrict__ p1h,
    _Float16* __restrict__ p1l, _Float16* __restrict__ p2h,
    _Float16* __restrict__ p2l, float* __restrict__ bns) {
  const int r = blockIdx.x, t = threadIdx.x;
  if (r == 656) {
    for (int u = t; u < 768; u += 64) bns[u] = gma[u] / sqrtf(var[u] + 1e-5f);
    for (int u = t; u < 512; u += 64)
      bns[768 + u] = pg[u] / sqrtf(pv[u] + 1e-5f);
    return;
  }
  const float* src;
  _Float16 *dh, *dl;
  int ot, ks, nks, K;
  if (r < 144) {
    src = w1; dh = w1h; dl = w1l; ot = r / 9; ks = r % 9; nks = 9; K = 259;
  } else if (r < 272) {
    const int rr = r - 144;
    src = w2; dh = w2h; dl = w2l; ot = rr >> 3; ks = rr & 7; nks = 8; K = 256;
  } else if (r < 400) {
    const int rr = r - 272;
    src = w3; dh = w3h; dl = w3l; ot = rr >> 3; ks = rr & 7; nks = 8; K = 256;
  } else if (r < 528) {
    const int rr = r - 400;
    src = pw1; dh = p1h; dl = p1l; ot = rr >> 3; ks = rr & 7; nks = 8; K = 256;
  } else {
    const int rr = r - 528;
    src = pw2; dh = p2h; dl = p2l; ot = rr >> 3; ks = rr & 7; nks = 8; K = 256;
  }
  const int m = t & 15, q = t >> 4;
  const float* row = src + (ot * 16 + m) * K;
  half8 vh, vl;
#pragma unroll
  for (int j = 0; j < 8; j++) {
    const int c = ks * 32 + q * 8 + j;
    const float v = (c < K) ? row[c] : 0.f;
    const _Float16 hi = (_Float16)v;
    vh[j] = hi;
    vl[j] = (_Float16)(v - (float)hi);
  }
  const int base = ((ot * nks + ks) * 64 + t) * 8;
  *(half8*)&dh[base] = vh;
  *(half8*)&dl[base] = vl;
}

// ---------------------------------------------------------------- FPS ------
// One wave per batch, all-register, barrier-free (validated bit-exact).
__global__ __launch_bounds__(64) void fps_kernel(const float* __restrict__ xyz,
                                                 float* __restrict__ new_xyz) {
  const int b = blockIdx.x, lane = threadIdx.x;
  const float* xb = xyz + b * K_ * 3;
  __shared__ __align__(16) float4 pts[K_];  // 32 KB
  float px[32], py[32], pz[32], dist[32];
#pragma unroll
  for (int j = 0; j < 32; j++) {
    const int k = lane + 64 * j;
    const float x = xb[3 * k + 0];
    const float yv = xb[3 * k + 1];
    const float z = xb[3 * k + 2];
    px[j] = x; py[j] = yv; pz[j] = z;
    dist[j] = 1e10f;
    pts[k] = make_float4(x, yv, z, 0.f);
  }
  __syncthreads();
  int far = 0;
  for (int i = 0; i < P_; i++) {
    const float4 c = pts[far];  // uniform address -> LDS broadcast
    if (lane == 0) {
      float* nx = new_xyz + (b * P_ + i) * 3;
      nx[0] = c.x; nx[1] = c.y; nx[2] = c.z;
    }
    float bv = -1.f;
    int bj = 0;
#pragma unroll
    for (int j = 0; j < 32; j++) {
      const float d = sqdist_rn(px[j], py[j], pz[j], c.x, c.y, c.z);
      dist[j] = fminf(dist[j], d);
      if (dist[j] > bv) { bv = dist[j]; bj = j; }  // strict > keeps lowest j
    }
    const unsigned kg = (unsigned)(bj * 64 + lane);
    unsigned long long key =
        ((unsigned long long)__float_as_uint(bv) << 32) |
        (unsigned long long)(0xFFFFFFFFu - kg);
#pragma unroll
    for (int off = 1; off < 64; off <<= 1) {
      const unsigned long long o = __shfl_xor(key, off);
      key = (o > key) ? o : key;
    }
    far = (int)(0xFFFFFFFFu - (unsigned)(key & 0xFFFFFFFFull));
  }
}

// ---------------------------------------------------------- ball query -----
__global__ __launch_bounds__(256) void ballq_kernel(const float* __restrict__ xyz,
                                                    const float* __restrict__ new_xyz,
                                                    int* __restrict__ idxw) {
  const int b = blockIdx.x, t = threadIdx.x;
  __shared__ __align__(16) float pts[K_ * 4];
  const float* xb = xyz + b * K_ * 3;
#pragma unroll
  for (int j = 0; j < 8; j++) {
    int k = t + 256 * j;
    pts[4 * k + 0] = xb[3 * k + 0];
    pts[4 * k + 1] = xb[3 * k + 1];
    pts[4 * k + 2] = xb[3 * k + 2];
    pts[4 * k + 3] = 0.f;
  }
  __syncthreads();
  const float r2 = (float)(0.3 * 0.3);
  const int p = t;
  const float nx = new_xyz[(b * P_ + p) * 3 + 0];
  const float ny = new_xyz[(b * P_ + p) * 3 + 1];
  const float nz = new_xyz[(b * P_ + p) * 3 + 2];
  int* ob = idxw + (b * P_ + p) * S_;
  int cnt = 0, first = 0;
  for (int k = 0; k < K_; k++) {
    if (cnt >= S_) break;
    const float4 q = *(const float4*)&pts[4 * k];
    float d2 = sqdist_rn(q.x, q.y, q.z, nx, ny, nz);
    if (d2 < r2) {
      if (cnt == 0) first = k;
      ob[cnt] = k;
      cnt++;
    }
  }
  for (int s = cnt; s < S_; s++) ob[s] = first;
}

// ------------------------------------------------------------- SA MLP ------
// Split-f16 MFMA: D = Wh*Xh + Wh*Xl + Wl*Xh (error ~2^-22). 2 proposals
// (32 samples)/block, 4 waves; wave w: o-tiles 4w..4w+3, both s-tiles.
__global__ __launch_bounds__(256, 2) void sa_kernel(
    const float* __restrict__ xyz, const float* __restrict__ features,
    const _Float16* __restrict__ w1h, const _Float16* __restrict__ w1l,
    const _Float16* __restrict__ w2h, const _Float16* __restrict__ w2l,
    const _Float16* __restrict__ w3h, const _Float16* __restrict__ w3l,
    const float* __restrict__ bns, const float* __restrict__ mu,
    const float* __restrict__ bta, const float* __restrict__ new_xyz,
    const int* __restrict__ idxw, float* __restrict__ y) {
  const int blk = blockIdx.x;  // 4096
  const int b = blk >> 7, p0 = (blk & 127) * 2, t = threadIdx.x;
  __shared__ __align__(16) _Float16 X1h[32 * 296];
  __shared__ __align__(16) _Float16 X1l[32 * 296];
  __shared__ __align__(16) _Float16 X2h[32 * 264];
  __shared__ __align__(16) _Float16 X2l[32 * 264];
  __shared__ __align__(16) float red[2 * 256];
  __shared__ int k_sh[32];

  if (t < 32) k_sh[t] = idxw[(b * P_ + p0) * S_ + t];
  for (int u = t; u < 32 * 32; u += 256) {
    const int s = u >> 5, cc = 256 + (u & 31);
    if (cc >= 259) {
      X1h[s * 296 + cc] = (_Float16)0.f;
      X1l[s * 296 + cc] = (_Float16)0.f;
    }
  }
  __syncthreads();
  if (t < 32) {
    const int pl = t >> 4, k = k_sh[t];
    const float* xb = xyz + b * K_ * 3;
    const float* nx = new_xyz + (b * P_ + p0 + pl) * 3;
#pragma unroll
    for (int c = 0; c < 3; c++) {
      const float v = (xb[3 * k + c] - nx[c]) / 0.3f;
      const _Float16 hi = (_Float16)v;
      X1h[t * 296 + c] = hi;
      X1l[t * 296 + c] = (_Float16)(v - (float)hi);
    }
  }
  {
    const float* fb = features + (size_t)b * C_ * K_ + (size_t)t * K_;
    const int c = 3 + t;
#pragma unroll 8
    for (int s = 0; s < 32; s++) {
      const float v = fb[k_sh[s]];
      const _Float16 hi = (_Float16)v;
      X1h[s * 296 + c] = hi;
      X1l[s * 296 + c] = (_Float16)(v - (float)hi);
    }
  }

  const int lane = t & 63, w = t >> 6;
  const int m = lane & 15, q = lane >> 4;

  f32x4 acc[4][2];
  half8 pAh[4], pAl[4];
#pragma unroll
  for (int i = 0; i < 4; i++) {
    const int off = (((4 * w + i) * 9) * 64 + lane) * 8;
    pAh[i] = *(const half8*)&w1h[off];
    pAl[i] = *(const half8*)&w1l[off];
  }
  __syncthreads();

#pragma unroll
  for (int l = 0; l < 3; l++) {
    const _Float16* Xih = (l == 1) ? X2h : X1h;
    const _Float16* Xil = (l == 1) ? X2l : X1l;
    const int XS = (l == 1) ? 264 : 296;
    const int nks = (l == 0) ? 9 : 8;
#pragma unroll
    for (int i = 0; i < 4; i++) {
      acc[i][0] = (f32x4){0.f, 0.f, 0.f, 0.f};
      acc[i][1] = (f32x4){0.f, 0.f, 0.f, 0.f};
    }
    for (int ks = 0; ks < nks; ks++) {
      half8 Ah[4], Al[4];
#pragma unroll
      for (int i = 0; i < 4; i++) { Ah[i] = pAh[i]; Al[i] = pAl[i]; }
      {
        int ln = l, kn = ks + 1;
        if (kn == nks) { ln = l + 1; kn = 0; }
        if (ln < 3) {
          const _Float16* Ph = (ln == 0) ? w1h : (ln == 1) ? w2h : w3h;
          const _Float16* Pl = (ln == 0) ? w1l : (ln == 1) ? w2l : w3l;
          const int nk2 = (ln == 0) ? 9 : 8;
#pragma unroll
          for (int i = 0; i < 4; i++) {
            const int off = (((4 * w + i) * nk2 + kn) * 64 + lane) * 8;
            pAh[i] = *(const half8*)&Ph[off];
            pAl[i] = *(const half8*)&Pl[off];
          }
        }
      }
      const int xo = ks * 32 + q * 8;
      const half8 Bh0 = *(const half8*)&Xih[m * XS + xo];
      const half8 Bl0 = *(const half8*)&Xil[m * XS + xo];
      const half8 Bh1 = *(const half8*)&Xih[(16 + m) * XS + xo];
      const half8 Bl1 = *(const half8*)&Xil[(16 + m) * XS + xo];
#pragma unroll
      for (int i = 0; i < 4; i++) {
        acc[i][0] = MFMA16(Ah[i], Bh0, acc[i][0], 0, 0, 0);
        acc[i][0] = MFMA16(Ah[i], Bl0, acc[i][0], 0, 0, 0);
        acc[i][0] = MFMA16(Al[i], Bh0, acc[i][0], 0, 0, 0);
        acc[i][1] = MFMA16(Ah[i], Bh1, acc[i][1], 0, 0, 0);
        acc[i][1] = MFMA16(Ah[i], Bl1, acc[i][1], 0, 0, 0);
        acc[i][1] = MFMA16(Al[i], Bh1, acc[i][1], 0, 0, 0);
      }
    }

    if (l < 2) {
      _Float16* Xoh = (l == 0) ? X2h : X1h;
      _Float16* Xol = (l == 0) ? X2l : X1l;
      const int XSo = (l == 0) ? 264 : 296;
#pragma unroll
      for (int i = 0; i < 4; i++) {
        const int ob = (4 * w + i) * 16 + q * 4;
        const f32x4 sc4 = *(const f32x4*)&bns[l * 256 + ob];
        const f32x4 m4 = *(const f32x4*)&mu[l * 256 + ob];
        const f32x4 b4 = *(const f32x4*)&bta[l * 256 + ob];
#pragma unroll
        for (int s = 0; s < 2; s++) {
          half4h vh, vl;
#pragma unroll
          for (int r = 0; r < 4; r++) {
            const float v = fmaxf((acc[i][s][r] - m4[r]) * sc4[r] + b4[r], 0.f);
            const _Float16 hi = (_Float16)v;
            vh[r] = hi;
            vl[r] = (_Float16)(v - (float)hi);
          }
          const int scol = s * 16 + m;
          *(half4h*)&Xoh[scol * XSo + ob] = vh;
          *(half4h*)&Xol[scol * XSo + ob] = vl;
        }
      }
      __syncthreads();
    } else {
#pragma unroll
      for (int i = 0; i < 4; i++)
#pragma unroll
        for (int s = 0; s < 2; s++)
#pragma unroll
          for (int r = 0; r < 4; r++) {
            float v = acc[i][s][r];
            v = fmaxf(v, __shfl_xor(v, 1));
            v = fmaxf(v, __shfl_xor(v, 2));
            v = fmaxf(v, __shfl_xor(v, 4));
            v = fmaxf(v, __shfl_xor(v, 8));
            acc[i][s][r] = v;
          }
      if (m == 0) {
#pragma unroll
        for (int i = 0; i < 4; i++) {
          const int ob = (4 * w + i) * 16 + q * 4;
          *(f32x4*)&red[ob] = acc[i][0];
          *(f32x4*)&red[256 + ob] = acc[i][1];
        }
      }
      __syncthreads();
      const float sc2 = bns[512 + t];
      const float mu2 = mu[512 + t], bt2 = bta[512 + t];
#pragma unroll
      for (int pl = 0; pl < 2; pl++) {
        const float raw = red[pl * 256 + t];
        y[(b * P_ + p0 + pl) * 256 + t] = fmaxf((raw - mu2) * sc2 + bt2, 0.f);
      }
    }
  }
}

// ------------------------------------------------- P-layers + all heads ----
// l0/l1: split-f16 MFMA (sa-proven; noise enters obj only through 2 BN+ReLU
// layers). l2 (obj-producing 119x256): EXACT round-7 f32 path, reading f32
// Y2 — no direct perturbation on argmin(obj). Round-6 bug (net_s stride 124
// vs ob<=127 collision) eliminated: l2 writes only o<119, stride 120.
__global__ __launch_bounds__(256, 2) void phead_kernel(
    const float* __restrict__ y, const _Float16* __restrict__ p1h,
    const _Float16* __restrict__ p1l, const _Float16* __restrict__ p2h,
    const _Float16* __restrict__ p2l, const float* __restrict__ pw3,
    const float* __restrict__ pb3, const float* __restrict__ bns,
    const float* __restrict__ pm, const float* __restrict__ pb,
    const float* __restrict__ new_xyz, const float* __restrict__ msa,
    float* __restrict__ out) {
  const int blk = blockIdx.x;  // 512
  const int b = blk >> 4, p0 = (blk & 15) * 16, t = threadIdx.x;
  // hand-packed LDS: Wt (l2 only) aliases X0/H (dead by l2)
  __shared__ __align__(16) char smem[58624];
  _Float16* X0h = (_Float16*)smem;             // 16*264*2 = 8448
  _Float16* X0l = (_Float16*)(smem + 8448);    // 8448
  _Float16* Hh  = (_Float16*)(smem + 16896);   // 8448
  _Float16* Hl  = (_Float16*)(smem + 25344);   // 8448 (ends 33792)
  float*    Wt  = (float*)smem;                // 256*20*4 = 20480 (alias)
  float*    Y2  = (float*)(smem + 33792);      // 16*260*4 = 16640
  float*    net_s = (float*)(smem + 50432);    // 16*120*4 = 7680

  {
#pragma unroll 4
    for (int s = 0; s < 16; s++) {
      const float v = y[(size_t)(b * P_ + p0 + s) * C_ + t];
      const _Float16 hi = (_Float16)v;
      X0h[s * 264 + t] = hi;
      X0l[s * 264 + t] = (_Float16)(v - (float)hi);
    }
  }
  const int lane = t & 63, w = t >> 6;
  const int m = lane & 15, q = lane >> 4;

  f32x4 acc[4];
  half8 pAh[4], pAl[4];
#pragma unroll
  for (int i = 0; i < 4; i++) {
    const int off = (((4 * w + i) * 8) * 64 + lane) * 8;
    pAh[i] = *(const half8*)&p1h[off];
    pAl[i] = *(const half8*)&p1l[off];
  }
  __syncthreads();

#pragma unroll
  for (int l = 0; l < 2; l++) {
    const _Float16* Xih = l ? Hh : X0h;
    const _Float16* Xil = l ? Hl : X0l;
#pragma unroll
    for (int i = 0; i < 4; i++) acc[i] = (f32x4){0.f, 0.f, 0.f, 0.f};
    for (int ks = 0; ks < 8; ks++) {
      half8 Ah[4], Al[4];
#pragma unroll
      for (int i = 0; i < 4; i++) { Ah[i] = pAh[i]; Al[i] = pAl[i]; }
      {
        int ln = l, kn = ks + 1;
        if (kn == 8) { ln = l + 1; kn = 0; }
        if (ln < 2) {
          const _Float16* Ph = ln ? p2h : p1h;
          const _Float16* Pl = ln ? p2l : p1l;
#pragma unroll
          for (int i = 0; i < 4; i++) {
            const int off = (((4 * w + i) * 8 + kn) * 64 + lane) * 8;
            pAh[i] = *(const half8*)&Ph[off];
            pAl[i] = *(const half8*)&Pl[off];
          }
        }
      }
      const int xo = ks * 32 + q * 8;
      const half8 Bh = *(const half8*)&Xih[m * 264 + xo];
      const half8 Bl = *(const half8*)&Xil[m * 264 + xo];
#pragma unroll
      for (int i = 0; i < 4; i++) {
        acc[i] = MFMA16(Ah[i], Bh, acc[i], 0, 0, 0);
        acc[i] = MFMA16(Ah[i], Bl, acc[i], 0, 0, 0);
        acc[i] = MFMA16(Al[i], Bh, acc[i], 0, 0, 0);
      }
    }
    // epilogue: BN + ReLU; l0 -> H (f16 split), l1 -> Y2 (f32)
#pragma unroll
    for (int i = 0; i < 4; i++) {
      const int ob = (4 * w + i) * 16 + q * 4;
      const f32x4 sc4 = *(const f32x4*)&bns[768 + l * 256 + ob];
      const f32x4 m4 = *(const f32x4*)&pm[l * 256 + ob];
      const f32x4 b4 = *(const f32x4*)&pb[l * 256 + ob];
      if (l == 0) {
        half4h vh, vl;
#pragma unroll
        for (int r = 0; r < 4; r++) {
          const float v = fmaxf((acc[i][r] - m4[r]) * sc4[r] + b4[r], 0.f);
          const _Float16 hi = (_Float16)v;
          vh[r] = hi;
          vl[r] = (_Float16)(v - (float)hi);
        }
        *(half4h*)&Hh[m * 264 + ob] = vh;
        *(half4h*)&Hl[m * 264 + ob] = vl;
      } else {
        f32x4 r4;
#pragma unroll
        for (int r = 0; r < 4; r++)
          r4[r] = fmaxf((acc[i][r] - m4[r]) * sc4[r] + b4[r], 0.f);
        *(f32x4*)&Y2[m * 260 + ob] = r4;
      }
    }
    __syncthreads();
  }

  // final layer (f32, round-7-exact): 119 outputs from Y2; Wt aliases X0/H
  {
    const int o = t & 127, ph = t >> 7;
    float a3[8];
#pragma unroll
    for (int pp = 0; pp < 8; pp++) a3[pp] = 0.f;
    for (int tile = 0; tile < 16; tile++) {
      const int c0 = tile * 16;
      for (int u = t; u < 119 * 4; u += 256) {
        int oo = u >> 2, qq = u & 3;
        *(float4*)&Wt[oo * 20 + qq * 4] =
            *(const float4*)(pw3 + oo * 256 + c0 + qq * 4);
      }
      __syncthreads();
      if (o < 119) {
#pragma unroll
        for (int j4 = 0; j4 < 4; j4++) {
          const float4 wv = *(const float4*)&Wt[o * 20 + j4 * 4];
#pragma unroll
          for (int pp = 0; pp < 8; pp++) {
            const float4 xv =
                *(const float4*)&Y2[(ph * 8 + pp) * 260 + c0 + j4 * 4];
            a3[pp] = fmaf(wv.x, xv.x, a3[pp]);
            a3[pp] = fmaf(wv.y, xv.y, a3[pp]);
            a3[pp] = fmaf(wv.z, xv.z, a3[pp]);
            a3[pp] = fmaf(wv.w, xv.w, a3[pp]);
          }
        }
      }
      __syncthreads();
    }
    if (o < 119) {
      const float bb = pb3[o];
#pragma unroll
      for (int pp = 0; pp < 8; pp++)
        net_s[(ph * 8 + pp) * 120 + o] = a3[pp] + bb;
    }
  }
  __syncthreads();

  if (t < 16) {
    const int gi = b * P_ + p0 + t;
    const float* nr = &net_s[t * 120];
    const float nx = new_xyz[gi * 3 + 0];
    const float ny = new_xyz[gi * 3 + 1];
    const float nz = new_xyz[gi * 3 + 2];
    const float obj0 = nr[0], obj1 = nr[1];
    out[OFF0 + gi * 2 + 0] = obj0;
    out[OFF0 + gi * 2 + 1] = obj1;
    const float cx = nx + nr[2], cy = ny + nr[3], cz = nz + nr[4];
    out[OFF1 + gi * 3 + 0] = cx;
    out[OFF1 + gi * 3 + 1] = cy;
    out[OFF1 + gi * 3 + 2] = cz;
    float bv = -1e30f;
    int bi = 0;
#pragma unroll
    for (int i = 0; i < 18; i++) {
      float v = nr[29 + i];
      out[OFF2 + gi * 18 + i] = v;
      if (v > bv) { bv = v; bi = i; }
    }
#pragma unroll
    for (int i = 0; i < 18; i++)
#pragma unroll
      for (int j = 0; j < 3; j++)
        out[OFF3 + gi * 54 + i * 3 + j] =
            __fmul_rn(nr[47 + i * 3 + j], msa[i * 3 + j]);
    float ps[3];
#pragma unroll
    for (int j = 0; j < 3; j++) {
      ps[j] = __fadd_rn(__fmul_rn(nr[47 + bi * 3 + j], msa[bi * 3 + j]),
                        msa[bi * 3 + j]);
      out[OFF4 + gi * 3 + j] = ps[j];
    }
    float sm = -1e30f;
#pragma unroll
    for (int i = 0; i < 18; i++) {
      float v = nr[101 + i];
      out[OFF5 + gi * 18 + i] = v;
      out[OFF7 + gi * 19 + i] = v;
      sm = fmaxf(sm, v);
    }
    out[OFF7 + gi * 19 + 18] = (obj0 <= obj1) ? 0.f : 1e10f;
    const float cc0 = cx, cc1 = cz, cc2 = -cy;
    const float sxk[8] = {1, 1, -1, -1, 1, 1, -1, -1};
    const float syk[8] = {1, 1, 1, 1, -1, -1, -1, -1};
    const float szk[8] = {1, -1, -1, 1, 1, -1, -1, 1};
#pragma unroll
    for (int k = 0; k < 8; k++) {
      out[OFF6 + gi * 24 + 3 * k + 0] = cc0 + ps[0] * sxk[k] * 0.5f;
      out[OFF6 + gi * 24 + 3 * k + 1] = cc1 + ps[2] * syk[k] * 0.5f;
      out[OFF6 + gi * 24 + 3 * k + 2] = cc2 + ps[1] * szk[k] * 0.5f;
    }
    {
      const float m2 = fmaxf(obj0, obj1);
      const float e0 = expf(obj0 - m2), e1 = expf(obj1 - m2);
      out[OFF8 + gi] = e1 / (e0 + e1);
    }
    {
      float ev[18], es = 0.f;
#pragma unroll
      for (int i = 0; i < 18; i++) {
        ev[i] = expf(nr[101 + i] - sm);
        es += ev[i];
      }
#pragma unroll
      for (int i = 0; i < 18; i++) out[OFF9 + gi * 18 + i] = ev[i] / es;
    }
  }
}

// ---------------------------------------------------------------------------
extern "C" void kernel_launch(void* const* d_in, const int* in_sizes, int n_in,
                              void* d_out, int out_size, void* d_ws,
                              size_t ws_size, hipStream_t stream) {
  (void)in_sizes; (void)n_in; (void)out_size; (void)ws_size;
  const float* xyz      = (const float*)d_in[0];
  const float* features = (const float*)d_in[1];
  const float* w1       = (const float*)d_in[2];
  const float* w2       = (const float*)d_in[3];
  const float* w3       = (const float*)d_in[4];
  const float* gma      = (const float*)d_in[5];
  const float* bta      = (const float*)d_in[6];
  const float* mu       = (const float*)d_in[7];
  const float* var      = (const float*)d_in[8];
  const float* pw1      = (const float*)d_in[9];
  const float* pw2      = (const float*)d_in[10];
  const float* pw3      = (const float*)d_in[11];
  const float* pb3      = (const float*)d_in[12];
  const float* pg       = (const float*)d_in[13];
  const float* pb       = (const float*)d_in[14];
  const float* pm       = (const float*)d_in[15];
  const float* pv       = (const float*)d_in[16];
  const float* msa      = (const float*)d_in[17];
  float* out = (float*)d_out;

  char* ws = (char*)d_ws;
  float*     new_xyz = (float*)ws;                   // 98304 B
  int*       idxw    = (int*)(ws + 98304);           // 524288 B
  float*     yb      = (float*)(ws + 622592);        // 8388608 B
  _Float16*  w1h     = (_Float16*)(ws + 9011200);    // 147456 B
  _Float16*  w1l     = (_Float16*)(ws + 9158656);    // 147456 B
  _Float16*  w2h     = (_Float16*)(ws + 9306112);    // 131072 B
  _Float16*  w2l     = (_Float16*)(ws + 9437184);    // 131072 B
  _Float16*  w3h     = (_Float16*)(ws + 9568256);    // 131072 B
  _Float16*  w3l     = (_Float16*)(ws + 9699328);    // 131072 B
  float*     bns     = (float*)(ws + 9830400);       // 5120 B (1280 f)
  _Float16*  p1h     = (_Float16*)(ws + 9835520);    // 131072 B
  _Float16*  p1l     = (_Float16*)(ws + 9966592);    // 131072 B
  _Float16*  p2h     = (_Float16*)(ws + 10097664);   // 131072 B
  _Float16*  p2l     = (_Float16*)(ws + 10228736);   // 131072 B -> 10359808

  wsplit_kernel<<<657, 64, 0, stream>>>(w1, w2, w3, pw1, pw2, gma, var, pg,
                                        pv, w1h, w1l, w2h, w2l, w3h, w3l, p1h,
                                        p1l, p2h, p2l, bns);
  fps_kernel<<<B_, 64, 0, stream>>>(xyz, new_xyz);
  ballq_kernel<<<B_, 256, 0, stream>>>(xyz, new_xyz, idxw);
  sa_kernel<<<B_ * 128, 256, 0, stream>>>(xyz, features, w1h, w1l, w2h, w2l,
                                          w3h, w3l, bns, mu, bta, new_xyz,
                                          idxw, yb);
  phead_kernel<<<B_ * 16, 256, 0, stream>>>(yb, p1h, p1l, p2h, p2l, pw3, pb3,
                                            bns, pm, pb, new_xyz, msa, out);
}